// Round 4
// baseline (9654.607 us; speedup 1.0000x reference)
//
#include <hip/hip_runtime.h>
#include <hip/hip_bf16.h>

typedef __hip_bfloat16 bf16;
typedef __attribute__((ext_vector_type(8))) short short8;
typedef __attribute__((ext_vector_type(4))) float f32x4;

#define LN_EPS 1e-5f

static constexpr int Dk     = 256;   // model dim
static constexpr int Tk     = 2048;  // seq len
static constexpr int Bk     = 4;     // batch
static constexpr int BTk    = 8192;  // B*T
static constexpr int MHk    = 2048;  // N/H
static constexpr int CHk    = 512;   // column chunk for y / update
static constexpr int LAYERS = 6;

// ---------------------------------------------------------------------------
__device__ __forceinline__ float wave_reduce(float v) {
#pragma unroll
    for (int o = 32; o > 0; o >>= 1) v += __shfl_down(v, o);
    return v;
}

__device__ __forceinline__ float block_sum_256(float x, float* sbuf) {
    float s = wave_reduce(x);
    int lane = threadIdx.x & 63, wv = threadIdx.x >> 6;
    if (lane == 0) sbuf[wv] = s;
    __syncthreads();
    float r = sbuf[0] + sbuf[1] + sbuf[2] + sbuf[3];
    __syncthreads();
    return r;
}

__device__ __forceinline__ void split_bf16(float x, bf16* h, bf16* l) {
    bf16 hh = (bf16)x;
    *h = hh;
    *l = (bf16)(x - (float)hh);
}

// ---------------------------------------------------------------------------
// Input dtype sniffer (insurance): fp32 inputs -> low halfwords have uniform
// bf16-exponent bits (~50% >= 2); bf16 N(0,0.02) inputs never reach |x|>=2.
__global__ __launch_bounds__(256) void sniff_kernel(const unsigned short* __restrict__ w,
                                                    int* __restrict__ flag) {
    __shared__ float sbuf[4];
    int tid = threadIdx.x;
    float cnt = 0.f;
    for (int i = tid; i < 1024; i += 256) {
        int e = (w[i] >> 7) & 0xFF;
        if (e >= 128) cnt += 1.f;
    }
    float tot = block_sum_256(cnt, sbuf);
    if (tid == 0) *flag = (tot > 32.f) ? 1 : 0;   // 1 = inputs are fp32
}

// weights -> hi/lo bf16 split (lo = 0 automatically if input already bf16)
__global__ __launch_bounds__(256) void cvt_split_kernel(const void* __restrict__ src,
                                                        const int* __restrict__ flag,
                                                        bf16* __restrict__ oh,
                                                        bf16* __restrict__ ol, int n) {
    bool f32 = (*flag != 0);
    for (int i = blockIdx.x * 256 + threadIdx.x; i < n; i += gridDim.x * 256) {
        float x = f32 ? ((const float*)src)[i] : (float)((const bf16*)src)[i];
        split_bf16(x, &oh[i], &ol[i]);
    }
}

// ---------------------------------------------------------------------------
// v = layernorm(wte[idx]); write fp32 v and hi/lo bf16 pair
__global__ __launch_bounds__(256) void embed_ln_kernel(const int* __restrict__ idx,
                                                       const void* __restrict__ wte,
                                                       const int* __restrict__ flag,
                                                       float* __restrict__ v,
                                                       bf16* __restrict__ vh,
                                                       bf16* __restrict__ vl) {
    __shared__ float sbuf[4];
    int bt = blockIdx.x, tid = threadIdx.x;
    int id = idx[bt];
    bool f32 = (*flag != 0);
    float x = f32 ? ((const float*)wte)[id * Dk + tid]
                  : (float)((const bf16*)wte)[id * Dk + tid];
    float mu = block_sum_256(x, sbuf) * (1.f / 256.f);
    float d = x - mu;
    float var = block_sum_256(d * d, sbuf) * (1.f / 256.f);
    float r = d * rsqrtf(var + LN_EPS);
    v[bt * Dk + tid] = r;
    split_bf16(r, &vh[bt * Dk + tid], &vl[bt * Dk + tid]);
}

// lnab = layernorm(a) -> hi/lo pair
__global__ __launch_bounds__(256) void ln_rows_kernel(const float* __restrict__ a,
                                                      bf16* __restrict__ oh,
                                                      bf16* __restrict__ ol) {
    __shared__ float sbuf[4];
    int bt = blockIdx.x, tid = threadIdx.x;
    float x = a[bt * Dk + tid];
    float mu = block_sum_256(x, sbuf) * (1.f / 256.f);
    float d = x - mu;
    float var = block_sum_256(d * d, sbuf) * (1.f / 256.f);
    float r = d * rsqrtf(var + LN_EPS);
    split_bf16(r, &oh[bt * Dk + tid], &ol[bt * Dk + tid]);
}

// v += layernorm(upd); refresh hi/lo pair
__global__ __launch_bounds__(256) void add_ln_kernel(const float* __restrict__ upd,
                                                     float* __restrict__ v,
                                                     bf16* __restrict__ vh,
                                                     bf16* __restrict__ vl) {
    __shared__ float sbuf[4];
    int bt = blockIdx.x, tid = threadIdx.x;
    float x = upd[bt * Dk + tid];
    float mu = block_sum_256(x, sbuf) * (1.f / 256.f);
    float d = x - mu;
    float var = block_sum_256(d * d, sbuf) * (1.f / 256.f);
    float r = d * rsqrtf(var + LN_EPS);
    float nv = v[bt * Dk + tid] + r;
    v[bt * Dk + tid] = nv;
    split_bf16(nv, &vh[bt * Dk + tid], &vl[bt * Dk + tid]);
}

// RoPE from fp32 v -> hi/lo pair (Q == K)
__global__ __launch_bounds__(128) void rope_kernel(const float* __restrict__ v,
                                                   bf16* __restrict__ qh,
                                                   bf16* __restrict__ ql) {
    int bt = blockIdx.x, i = threadIdx.x;      // i in [0,128)
    int t = bt & (Tk - 1);
    float invf = powf(10000.f, -(float)i / 128.f);
    float ang = (float)t * invf;
    float s, c;
    sincosf(ang, &s, &c);
    float q1 = v[bt * Dk + i];
    float q2 = v[bt * Dk + 128 + i];
    float r1 = q1 * c - q2 * s;
    float r2 = q2 * c + q1 * s;
    split_bf16(r1, &qh[bt * Dk + i],       &ql[bt * Dk + i]);
    split_bf16(r2, &qh[bt * Dk + 128 + i], &ql[bt * Dk + 128 + i]);
}

// ---------------------------------------------------------------------------
// Fully compensated bf16 GEMM: C = (Ah+Al)(Bh+Bl) ~= AhBh + AhBl + AlBh.
// BLAY=0: B row-major [K][N]; BLAY=1: B transposed [N][K].
// EPI=0: store fp32 to Cf (ACC=1 accumulates); EPI=3: causal mask (keep
//        row>=col), store hi/lo pair to Ch/Cl; above-diag blocks zero-fill.
// TRIK=1: K-loop limited to mb+64 (A cols zero beyond block diagonal).
// 64x64 tile, 4 waves, mfma_f32_16x16x32_bf16.
// Layouts (m89/m120-verified): A[m=lane&15][k=quad*8+j], B[n=lane&15][k=quad*8+j],
// C/D: col=lane&15, row=quad*4+reg.
template <int EPI, int BLAY, int TRIK, int ACC>
__global__ __launch_bounds__(256) void gemm3(
    const bf16* __restrict__ Ah, const bf16* __restrict__ Al, int lda,
    const bf16* __restrict__ Bh, const bf16* __restrict__ Bl, int ldb,
    float* __restrict__ Cf, bf16* __restrict__ Ch, bf16* __restrict__ Cl,
    int ldc, int K) {
    __shared__ __align__(16) short Ash[64 * 40];
    __shared__ __align__(16) short Asl[64 * 40];
    __shared__ __align__(16) short Bsh[64 * 40];
    __shared__ __align__(16) short Bsl[64 * 40];
    const int tid = threadIdx.x;
    const int lane = tid & 63, wv = tid >> 6;
    const int wr = wv >> 1, wc = wv & 1;
    const int quad = lane >> 4, r = lane & 15;
    const int mb = blockIdx.y * 64, nb = blockIdx.x * 64;

    if (EPI == 3 && (int)blockIdx.x > (int)blockIdx.y) {
#pragma unroll
        for (int e = 0; e < 16; e++) {
            int ii = e * 256 + tid;
            int rr = ii >> 6, cc = ii & 63;
            long long ci = (long long)(mb + rr) * ldc + nb + cc;
            Ch[ci] = (bf16)0.f;
            Cl[ci] = (bf16)0.f;
        }
        return;
    }

    f32x4 acc[2][2] = {};
    const int ar = tid >> 2, ak = (tid & 3) * 8;   // A stage: 64 rows x 32 k
    const int bk = tid >> 3, bn = (tid & 7) * 8;   // B stage (BLAY=0)
    const int Klim = TRIK ? (mb + 64) : K;
    for (int k0 = 0; k0 < Klim; k0 += 32) {
        *(short8*)&Ash[ar * 40 + ak] = *(const short8*)(Ah + (long long)(mb + ar) * lda + k0 + ak);
        *(short8*)&Asl[ar * 40 + ak] = *(const short8*)(Al + (long long)(mb + ar) * lda + k0 + ak);
        if (BLAY == 1) {
            *(short8*)&Bsh[ar * 40 + ak] = *(const short8*)(Bh + (long long)(nb + ar) * ldb + k0 + ak);
            *(short8*)&Bsl[ar * 40 + ak] = *(const short8*)(Bl + (long long)(nb + ar) * ldb + k0 + ak);
        } else {
            short8 bh = *(const short8*)(Bh + (long long)(k0 + bk) * ldb + nb + bn);
            short8 bl = *(const short8*)(Bl + (long long)(k0 + bk) * ldb + nb + bn);
#pragma unroll
            for (int j = 0; j < 8; j++) {
                Bsh[(bn + j) * 40 + bk] = bh[j];
                Bsl[(bn + j) * 40 + bk] = bl[j];
            }
        }
        __syncthreads();
        short8 bh0 = *(const short8*)&Bsh[(wc * 32 +  0 + r) * 40 + quad * 8];
        short8 bl0 = *(const short8*)&Bsl[(wc * 32 +  0 + r) * 40 + quad * 8];
        short8 bh1 = *(const short8*)&Bsh[(wc * 32 + 16 + r) * 40 + quad * 8];
        short8 bl1 = *(const short8*)&Bsl[(wc * 32 + 16 + r) * 40 + quad * 8];
#pragma unroll
        for (int mi = 0; mi < 2; mi++) {
            short8 ah = *(const short8*)&Ash[(wr * 32 + mi * 16 + r) * 40 + quad * 8];
            short8 al = *(const short8*)&Asl[(wr * 32 + mi * 16 + r) * 40 + quad * 8];
            acc[mi][0] = __builtin_amdgcn_mfma_f32_16x16x32_bf16(ah, bh0, acc[mi][0], 0, 0, 0);
            acc[mi][0] = __builtin_amdgcn_mfma_f32_16x16x32_bf16(ah, bl0, acc[mi][0], 0, 0, 0);
            acc[mi][0] = __builtin_amdgcn_mfma_f32_16x16x32_bf16(al, bh0, acc[mi][0], 0, 0, 0);
            acc[mi][1] = __builtin_amdgcn_mfma_f32_16x16x32_bf16(ah, bh1, acc[mi][1], 0, 0, 0);
            acc[mi][1] = __builtin_amdgcn_mfma_f32_16x16x32_bf16(ah, bl1, acc[mi][1], 0, 0, 0);
            acc[mi][1] = __builtin_amdgcn_mfma_f32_16x16x32_bf16(al, bh1, acc[mi][1], 0, 0, 0);
        }
        __syncthreads();
    }
#pragma unroll
    for (int mi = 0; mi < 2; mi++)
#pragma unroll
        for (int ni = 0; ni < 2; ni++) {
            int row0 = mb + wr * 32 + mi * 16 + quad * 4;
            int col = nb + wc * 32 + ni * 16 + r;
#pragma unroll
            for (int rr = 0; rr < 4; rr++) {
                float val = acc[mi][ni][rr];
                int row = row0 + rr;
                long long ci = (long long)row * ldc + col;
                if (EPI == 3) {
                    if (row < col) val = 0.f;
                    bf16 h, l;
                    split_bf16(val, &h, &l);
                    Ch[ci] = h;
                    Cl[ci] = l;
                } else {
                    Cf[ci] = ACC ? (Cf[ci] + val) : val;
                }
            }
        }
}

// ---------------------------------------------------------------------------
// Fused dual compensated GEMM:
//   y = relu((A1h+A1l)B1) * relu((A2h+A2l)B2), B split too; y stored hi/lo.
__global__ __launch_bounds__(256) void dual_gemm3(
    const bf16* __restrict__ A1h, const bf16* __restrict__ A1l,
    const bf16* __restrict__ A2h, const bf16* __restrict__ A2l,
    const bf16* __restrict__ B1h, const bf16* __restrict__ B1l,
    const bf16* __restrict__ B2h, const bf16* __restrict__ B2l, int ldb,
    bf16* __restrict__ Ch, bf16* __restrict__ Cl, int ldc, int K) {
    __shared__ __align__(16) short As1h[64 * 40];
    __shared__ __align__(16) short As1l[64 * 40];
    __shared__ __align__(16) short As2h[64 * 40];
    __shared__ __align__(16) short As2l[64 * 40];
    __shared__ __align__(16) short Bs1h[64 * 40];
    __shared__ __align__(16) short Bs1l[64 * 40];
    __shared__ __align__(16) short Bs2h[64 * 40];
    __shared__ __align__(16) short Bs2l[64 * 40];
    const int tid = threadIdx.x;
    const int lane = tid & 63, wv = tid >> 6;
    const int wr = wv >> 1, wc = wv & 1;
    const int quad = lane >> 4, r = lane & 15;
    const int mb = blockIdx.y * 64, nb = blockIdx.x * 64;
    const int lda = Dk;

    f32x4 accY[2][2] = {};
    f32x4 accX[2][2] = {};
    const int ar = tid >> 2, ak = (tid & 3) * 8;
    const int bk = tid >> 3, bn = (tid & 7) * 8;
    for (int k0 = 0; k0 < K; k0 += 32) {
        *(short8*)&As1h[ar * 40 + ak] = *(const short8*)(A1h + (long long)(mb + ar) * lda + k0 + ak);
        *(short8*)&As1l[ar * 40 + ak] = *(const short8*)(A1l + (long long)(mb + ar) * lda + k0 + ak);
        *(short8*)&As2h[ar * 40 + ak] = *(const short8*)(A2h + (long long)(mb + ar) * lda + k0 + ak);
        *(short8*)&As2l[ar * 40 + ak] = *(const short8*)(A2l + (long long)(mb + ar) * lda + k0 + ak);
        short8 b1h = *(const short8*)(B1h + (long long)(k0 + bk) * ldb + nb + bn);
        short8 b1l = *(const short8*)(B1l + (long long)(k0 + bk) * ldb + nb + bn);
        short8 b2h = *(const short8*)(B2h + (long long)(k0 + bk) * ldb + nb + bn);
        short8 b2l = *(const short8*)(B2l + (long long)(k0 + bk) * ldb + nb + bn);
#pragma unroll
        for (int j = 0; j < 8; j++) {
            Bs1h[(bn + j) * 40 + bk] = b1h[j];
            Bs1l[(bn + j) * 40 + bk] = b1l[j];
            Bs2h[(bn + j) * 40 + bk] = b2h[j];
            Bs2l[(bn + j) * 40 + bk] = b2l[j];
        }
        __syncthreads();
#pragma unroll
        for (int ni = 0; ni < 2; ni++) {
            short8 f1h = *(const short8*)&Bs1h[(wc * 32 + ni * 16 + r) * 40 + quad * 8];
            short8 f1l = *(const short8*)&Bs1l[(wc * 32 + ni * 16 + r) * 40 + quad * 8];
            short8 f2h = *(const short8*)&Bs2h[(wc * 32 + ni * 16 + r) * 40 + quad * 8];
            short8 f2l = *(const short8*)&Bs2l[(wc * 32 + ni * 16 + r) * 40 + quad * 8];
#pragma unroll
            for (int mi = 0; mi < 2; mi++) {
                short8 a1h = *(const short8*)&As1h[(wr * 32 + mi * 16 + r) * 40 + quad * 8];
                short8 a1l = *(const short8*)&As1l[(wr * 32 + mi * 16 + r) * 40 + quad * 8];
                short8 a2h = *(const short8*)&As2h[(wr * 32 + mi * 16 + r) * 40 + quad * 8];
                short8 a2l = *(const short8*)&As2l[(wr * 32 + mi * 16 + r) * 40 + quad * 8];
                accY[mi][ni] = __builtin_amdgcn_mfma_f32_16x16x32_bf16(a1h, f1h, accY[mi][ni], 0, 0, 0);
                accY[mi][ni] = __builtin_amdgcn_mfma_f32_16x16x32_bf16(a1h, f1l, accY[mi][ni], 0, 0, 0);
                accY[mi][ni] = __builtin_amdgcn_mfma_f32_16x16x32_bf16(a1l, f1h, accY[mi][ni], 0, 0, 0);
                accX[mi][ni] = __builtin_amdgcn_mfma_f32_16x16x32_bf16(a2h, f2h, accX[mi][ni], 0, 0, 0);
                accX[mi][ni] = __builtin_amdgcn_mfma_f32_16x16x32_bf16(a2h, f2l, accX[mi][ni], 0, 0, 0);
                accX[mi][ni] = __builtin_amdgcn_mfma_f32_16x16x32_bf16(a2l, f2h, accX[mi][ni], 0, 0, 0);
            }
        }
        __syncthreads();
    }
#pragma unroll
    for (int mi = 0; mi < 2; mi++)
#pragma unroll
        for (int ni = 0; ni < 2; ni++) {
            int row0 = mb + wr * 32 + mi * 16 + quad * 4;
            int col = nb + wc * 32 + ni * 16 + r;
#pragma unroll
            for (int rr = 0; rr < 4; rr++) {
                float yv = fmaxf(accY[mi][ni][rr], 0.f);
                float xv = fmaxf(accX[mi][ni][rr], 0.f);
                long long ci = (long long)(row0 + rr) * ldc + col;
                bf16 h, l;
                split_bf16(yv * xv, &h, &l);
                Ch[ci] = h;
                Cl[ci] = l;
            }
        }
}

// ---------------------------------------------------------------------------
extern "C" void kernel_launch(void* const* d_in, const int* in_sizes, int n_in,
                              void* d_out, int out_size, void* d_ws, size_t ws_size,
                              hipStream_t stream) {
    (void)in_sizes; (void)n_in; (void)out_size; (void)ws_size;
    const int* idx = (const int*)d_in[0];
    float* out = (float*)d_out;   // output is fp32 (reference is pure fp32)

    char* ws = (char*)d_ws;
    float* v32  = (float*)(ws);                    //  8 MiB [8192][256]
    bf16*  vh   = (bf16*)(ws + (8ll << 20));       //  4
    bf16*  vl   = (bf16*)(ws + (12ll << 20));      //  4
    bf16*  qh   = (bf16*)(ws + (16ll << 20));      //  4
    bf16*  ql   = (bf16*)(ws + (20ll << 20));      //  4
    float* a32  = (float*)(ws + (24ll << 20));     //  8
    bf16*  lnh  = (bf16*)(ws + (32ll << 20));      //  4
    bf16*  lnl  = (bf16*)(ws + (36ll << 20));      //  4
    float* upd  = (float*)(ws + (40ll << 20));     //  8
    bf16*  Eh   = (bf16*)(ws + (48ll << 20));      //  8 (one batch [2048][2048])
    bf16*  El   = (bf16*)(ws + (56ll << 20));      //  8
    bf16*  yh   = (bf16*)(ws + (64ll << 20));      //  8 (one chunk [8192][512])
    bf16*  yl   = (bf16*)(ws + (72ll << 20));      //  8
    bf16*  ench = (bf16*)(ws + (80ll << 20));      //  4
    bf16*  encl = (bf16*)(ws + (84ll << 20));      //  4
    bf16*  dxh  = (bf16*)(ws + (88ll << 20));      //  4
    bf16*  dxl  = (bf16*)(ws + (92ll << 20));      //  4
    bf16*  dyh  = (bf16*)(ws + (96ll << 20));      //  4
    bf16*  dyl  = (bf16*)(ws + (100ll << 20));     //  4
    bf16*  roh  = (bf16*)(ws + (104ll << 20));     //  128 KiB
    bf16*  rol  = (bf16*)(ws + (104ll << 20) + (256ll << 10));
    int*   flag = (int*)(ws + (105ll << 20));
    // total ~105 MiB

    sniff_kernel<<<1, 256, 0, stream>>>((const unsigned short*)d_in[1], flag);
    cvt_split_kernel<<<2048, 256, 0, stream>>>(d_in[2], flag, ench, encl, 8192 * Dk);
    cvt_split_kernel<<<2048, 256, 0, stream>>>(d_in[3], flag, dxh, dxl, 4 * Dk * MHk);
    cvt_split_kernel<<<2048, 256, 0, stream>>>(d_in[4], flag, dyh, dyl, 4 * Dk * MHk);
    cvt_split_kernel<<<256, 256, 0, stream>>>(d_in[5], flag, roh, rol, Dk * 256);

    embed_ln_kernel<<<BTk, 256, 0, stream>>>(idx, d_in[1], flag, v32, vh, vl);

    for (int l = 0; l < LAYERS; l++) {
        rope_kernel<<<BTk, 128, 0, stream>>>(v32, qh, ql);
        for (int b = 0; b < Bk; b++) {
            const long long qo = (long long)b * Tk * Dk;
            // E = tril((Qh+Ql)(Qh+Ql)^T), hi/lo bf16 out
            gemm3<3, 1, 0, 0><<<dim3(Tk / 64, Tk / 64), 256, 0, stream>>>(
                qh + qo, ql + qo, Dk, qh + qo, ql + qo, Dk,
                nullptr, Eh, El, Tk, Dk);
            // a = (Eh+El)(Vh+Vl), fp32 out; skip k-blocks beyond diagonal
            gemm3<0, 0, 1, 0><<<dim3(Dk / 64, Tk / 64), 256, 0, stream>>>(
                Eh, El, Tk, vh + qo, vl + qo, Dk,
                a32 + qo, nullptr, nullptr, Dk, Tk);
        }
        ln_rows_kernel<<<BTk, 256, 0, stream>>>(a32, lnh, lnl);
        bool first = true;
        for (int h = 0; h < 4; h++) {
            for (int c = 0; c < MHk / CHk; c++) {
                const long long wb = (long long)h * Dk * MHk + c * CHk;   // col offset in [D][M]
                dual_gemm3<<<dim3(CHk / 64, BTk / 64), 256, 0, stream>>>(
                    lnh, lnl, vh, vl,
                    dyh + wb, dyl + wb, dxh + wb, dxl + wb, MHk,
                    yh, yl, CHk, Dk);
                const long long eb = (long long)(h * MHk + c * CHk) * Dk; // row offset in [N][D]
                if (first) {
                    gemm3<0, 0, 0, 0><<<dim3(Dk / 64, BTk / 64), 256, 0, stream>>>(
                        yh, yl, CHk, ench + eb, encl + eb, Dk,
                        upd, nullptr, nullptr, Dk, CHk);
                    first = false;
                } else {
                    gemm3<0, 0, 0, 1><<<dim3(Dk / 64, BTk / 64), 256, 0, stream>>>(
                        yh, yl, CHk, ench + eb, encl + eb, Dk,
                        upd, nullptr, nullptr, Dk, CHk);
                }
            }
        }
        add_ln_kernel<<<BTk, 256, 0, stream>>>(upd, v32, vh, vl);
    }
    // logits = (vh+vl)(roh+rol) -> fp32 out
    gemm3<0, 0, 0, 0><<<dim3(256 / 64, BTk / 64), 256, 0, stream>>>(
        vh, vl, Dk, roh, rol, 256, out, nullptr, nullptr, 256, Dk);
}

// Round 5
// 6937.415 us; speedup vs baseline: 1.3917x; 1.3917x over previous
//
#include <hip/hip_runtime.h>
#include <hip/hip_bf16.h>

typedef __hip_bfloat16 bf16;
typedef __attribute__((ext_vector_type(8))) short short8;
typedef __attribute__((ext_vector_type(4))) float f32x4;

#define LN_EPS 1e-5f

static constexpr int Dk     = 256;   // model dim
static constexpr int Tk     = 2048;  // seq len
static constexpr int BTk    = 8192;  // B*T
static constexpr int MHk    = 2048;  // N/H
static constexpr int CHk    = 1024;  // hidden-column chunk
static constexpr int LAYERS = 6;

// ---------------------------------------------------------------------------
__device__ __forceinline__ float wave_reduce(float v) {
#pragma unroll
    for (int o = 32; o > 0; o >>= 1) v += __shfl_down(v, o);
    return v;
}

__device__ __forceinline__ float block_sum_256(float x, float* sbuf) {
    float s = wave_reduce(x);
    int lane = threadIdx.x & 63, wv = threadIdx.x >> 6;
    if (lane == 0) sbuf[wv] = s;
    __syncthreads();
    float r = sbuf[0] + sbuf[1] + sbuf[2] + sbuf[3];
    __syncthreads();
    return r;
}

__device__ __forceinline__ void split_bf16(float x, bf16* h, bf16* l) {
    bf16 hh = (bf16)x;
    *h = hh;
    *l = (bf16)(x - (float)hh);
}

// async global->LDS, 16B per lane. LDS dest must be wave-uniform base;
// HW appends lane*16. Layout must be load-order contiguous (no padding).
__device__ __forceinline__ void glds16(const bf16* g, bf16* lds_base_wave_uniform) {
    __builtin_amdgcn_global_load_lds(
        (__attribute__((address_space(1))) void*)g,
        (__attribute__((address_space(3))) void*)lds_base_wave_uniform,
        16, 0, 0);
}

// ---------------------------------------------------------------------------
// dtype sniffer (insurance): fp32 words reinterpreted as bf16 halfwords show
// exponents >=128 often; bf16 N(0,0.02) never.
__global__ __launch_bounds__(256) void sniff_kernel(const unsigned short* __restrict__ w,
                                                    int* __restrict__ flag) {
    __shared__ float sbuf[4];
    int tid = threadIdx.x;
    float cnt = 0.f;
    for (int i = tid; i < 1024; i += 256) {
        int e = (w[i] >> 7) & 0xFF;
        if (e >= 128) cnt += 1.f;
    }
    float tot = block_sum_256(cnt, sbuf);
    if (tid == 0) *flag = (tot > 32.f) ? 1 : 0;
}

// plain hi/lo split (no transpose) — readout weights
__global__ __launch_bounds__(256) void cvt_split_kernel(const void* __restrict__ src,
                                                        const int* __restrict__ flag,
                                                        bf16* __restrict__ oh,
                                                        bf16* __restrict__ ol, int n) {
    bool f32 = (*flag != 0);
    for (int i = blockIdx.x * 256 + threadIdx.x; i < n; i += gridDim.x * 256) {
        float x = f32 ? ((const float*)src)[i] : (float)((const bf16*)src)[i];
        split_bf16(x, &oh[i], &ol[i]);
    }
}

// Tiled transpose + hi/lo split: in [R][C] -> out [C][R], per z slice.
__global__ __launch_bounds__(256) void tr_split_kernel(const void* __restrict__ src,
                                                       const int* __restrict__ flag,
                                                       bf16* __restrict__ oh,
                                                       bf16* __restrict__ ol,
                                                       int R, int C,
                                                       long long sz, long long dz) {
    __shared__ float t[32][33];
    bool f32 = (*flag != 0);
    int ct = blockIdx.x * 32, rt = blockIdx.y * 32;
    long long so = (long long)blockIdx.z * sz, dofs = (long long)blockIdx.z * dz;
    int tx = threadIdx.x & 31, ty = threadIdx.x >> 5;   // ty 0..7
#pragma unroll
    for (int i = 0; i < 4; i++) {
        long long idx = so + (long long)(rt + ty + i * 8) * C + ct + tx;
        t[ty + i * 8][tx] = f32 ? ((const float*)src)[idx] : (float)((const bf16*)src)[idx];
    }
    __syncthreads();
#pragma unroll
    for (int i = 0; i < 4; i++) {
        long long odx = dofs + (long long)(ct + ty + i * 8) * R + rt + tx;
        split_bf16(t[tx][ty + i * 8], &oh[odx], &ol[odx]);
    }
}

// ---------------------------------------------------------------------------
// v = layernorm(wte[idx]); fp32 + hi/lo pair
__global__ __launch_bounds__(256) void embed_ln_kernel(const int* __restrict__ idx,
                                                       const void* __restrict__ wte,
                                                       const int* __restrict__ flag,
                                                       float* __restrict__ v,
                                                       bf16* __restrict__ vh,
                                                       bf16* __restrict__ vl) {
    __shared__ float sbuf[4];
    int bt = blockIdx.x, tid = threadIdx.x;
    int id = idx[bt];
    bool f32 = (*flag != 0);
    float x = f32 ? ((const float*)wte)[id * Dk + tid]
                  : (float)((const bf16*)wte)[id * Dk + tid];
    float mu = block_sum_256(x, sbuf) * (1.f / 256.f);
    float d = x - mu;
    float var = block_sum_256(d * d, sbuf) * (1.f / 256.f);
    float r = d * rsqrtf(var + LN_EPS);
    v[bt * Dk + tid] = r;
    split_bf16(r, &vh[bt * Dk + tid], &vl[bt * Dk + tid]);
}

__global__ __launch_bounds__(256) void ln_rows_kernel(const float* __restrict__ a,
                                                      bf16* __restrict__ oh,
                                                      bf16* __restrict__ ol) {
    __shared__ float sbuf[4];
    int bt = blockIdx.x, tid = threadIdx.x;
    float x = a[bt * Dk + tid];
    float mu = block_sum_256(x, sbuf) * (1.f / 256.f);
    float d = x - mu;
    float var = block_sum_256(d * d, sbuf) * (1.f / 256.f);
    float r = d * rsqrtf(var + LN_EPS);
    split_bf16(r, &oh[bt * Dk + tid], &ol[bt * Dk + tid]);
}

__global__ __launch_bounds__(256) void add_ln_kernel(const float* __restrict__ upd,
                                                     float* __restrict__ v,
                                                     bf16* __restrict__ vh,
                                                     bf16* __restrict__ vl) {
    __shared__ float sbuf[4];
    int bt = blockIdx.x, tid = threadIdx.x;
    float x = upd[bt * Dk + tid];
    float mu = block_sum_256(x, sbuf) * (1.f / 256.f);
    float d = x - mu;
    float var = block_sum_256(d * d, sbuf) * (1.f / 256.f);
    float r = d * rsqrtf(var + LN_EPS);
    float nv = v[bt * Dk + tid] + r;
    v[bt * Dk + tid] = nv;
    split_bf16(nv, &vh[bt * Dk + tid], &vl[bt * Dk + tid]);
}

__global__ __launch_bounds__(128) void rope_kernel(const float* __restrict__ v,
                                                   bf16* __restrict__ qh,
                                                   bf16* __restrict__ ql) {
    int bt = blockIdx.x, i = threadIdx.x;
    int t = bt & (Tk - 1);
    float invf = powf(10000.f, -(float)i / 128.f);
    float ang = (float)t * invf;
    float s, c;
    sincosf(ang, &s, &c);
    float q1 = v[bt * Dk + i];
    float q2 = v[bt * Dk + 128 + i];
    split_bf16(q1 * c - q2 * s, &qh[bt * Dk + i],       &ql[bt * Dk + i]);
    split_bf16(q2 * c + q1 * s, &qh[bt * Dk + 128 + i], &ql[bt * Dk + 128 + i]);
}

// ---------------------------------------------------------------------------
// 128x128 async MFMA GEMM, compensated via 3 K-segments (AhBh, AhBl, AlBh).
// A [M][K] row-major (lda); B [N][K] row-major (ldb) i.e. pre-transposed.
// EPI 0: causal energy — mask row<col, store hi/lo; blocks above diag zero-fill.
// EPI 1: relu -> hi/lo store.
// EPI 2: relu * (Ch+Cl at same ci) -> hi/lo store (in-place RMW).
// Proven m97 shape: BK=32, 2-barrier K-loop, glds width-16, unpadded LDS.
template <int EPI>
__global__ __launch_bounds__(256) void gemm128(
    const bf16* __restrict__ A0, const bf16* __restrict__ A1, int lda, long long az,
    const bf16* __restrict__ B0, const bf16* __restrict__ B1, int ldb, long long bz,
    bf16* __restrict__ Ch, bf16* __restrict__ Cl, int ldc, long long cz, int K) {
    __shared__ __align__(16) bf16 As[128 * 32];
    __shared__ __align__(16) bf16 Bs[128 * 32];
    const int tid = threadIdx.x;
    const int lane = tid & 63, wv = tid >> 6;
    const int wr = wv >> 1, wc = wv & 1;
    const int quad = lane >> 4, r = lane & 15;
    const int mb = blockIdx.y * 128, nb = blockIdx.x * 128;
    A0 += (long long)blockIdx.z * az; A1 += (long long)blockIdx.z * az;
    B0 += (long long)blockIdx.z * bz; B1 += (long long)blockIdx.z * bz;
    Ch += (long long)blockIdx.z * cz; Cl += (long long)blockIdx.z * cz;

    if (EPI == 0 && (int)blockIdx.x > (int)blockIdx.y) {
#pragma unroll
        for (int e = 0; e < 64; e++) {
            int ii = e * 256 + tid;
            long long ci = (long long)(mb + (ii >> 7)) * ldc + nb + (ii & 127);
            Ch[ci] = (bf16)0.f;
            Cl[ci] = (bf16)0.f;
        }
        return;
    }

    f32x4 acc[4][4] = {};
    const int srow = tid >> 2, skq = (tid & 3) * 8;          // staging row/kcol (round 0)
    const int wbase = (tid & 192) * 8;                       // wave-uniform LDS base (elems)
    const bf16* APs[3] = {A0, A0, A1};
    const bf16* BPs[3] = {B0, B1, B0};
#pragma unroll
    for (int seg = 0; seg < 3; seg++) {
        const bf16* Ap = APs[seg];
        const bf16* Bp = BPs[seg];
        for (int k0 = 0; k0 < K; k0 += 32) {
            // stage A,B tiles: 128x32 each, 2 glds rounds per tile
#pragma unroll
            for (int rnd = 0; rnd < 2; rnd++) {
                int row = rnd * 64 + srow;
                glds16(Ap + (long long)(mb + row) * lda + k0 + skq, As + rnd * 2048 + wbase);
                glds16(Bp + (long long)(nb + row) * ldb + k0 + skq, Bs + rnd * 2048 + wbase);
            }
            __syncthreads();
            short8 bfr[4];
#pragma unroll
            for (int ni = 0; ni < 4; ni++)
                bfr[ni] = *(const short8*)&Bs[(wc * 64 + ni * 16 + r) * 32 + quad * 8];
#pragma unroll
            for (int mi = 0; mi < 4; mi++) {
                short8 afr = *(const short8*)&As[(wr * 64 + mi * 16 + r) * 32 + quad * 8];
#pragma unroll
                for (int ni = 0; ni < 4; ni++)
                    acc[mi][ni] = __builtin_amdgcn_mfma_f32_16x16x32_bf16(afr, bfr[ni], acc[mi][ni], 0, 0, 0);
            }
            __syncthreads();
        }
    }
#pragma unroll
    for (int mi = 0; mi < 4; mi++)
#pragma unroll
        for (int ni = 0; ni < 4; ni++) {
            int row0 = mb + wr * 64 + mi * 16 + quad * 4;
            int col = nb + wc * 64 + ni * 16 + r;
#pragma unroll
            for (int rr = 0; rr < 4; rr++) {
                int row = row0 + rr;
                long long ci = (long long)row * ldc + col;
                float val = acc[mi][ni][rr];
                if (EPI == 0) {
                    if (row < col) val = 0.f;
                } else if (EPI == 1) {
                    val = fmaxf(val, 0.f);
                } else {
                    float xv = (float)Ch[ci] + (float)Cl[ci];
                    val = fmaxf(val, 0.f) * xv;
                }
                bf16 h, l;
                split_bf16(val, &h, &l);
                Ch[ci] = h;
                Cl[ci] = l;
            }
        }
}

// ---------------------------------------------------------------------------
// 64x64 async MFMA GEMM (segments), fp32 C store/accumulate. For update:
// A=y [M][K] (lda), B=enc^T [N][K] (ldb). FIRST=1 stores, else accumulates.
template <int FIRST>
__global__ __launch_bounds__(256) void gemm64u(
    const bf16* __restrict__ A0, const bf16* __restrict__ A1, int lda,
    const bf16* __restrict__ B0, const bf16* __restrict__ B1, int ldb,
    float* __restrict__ Cf, int ldc, int K) {
    __shared__ __align__(16) bf16 As[64 * 32];
    __shared__ __align__(16) bf16 Bs[64 * 32];
    const int tid = threadIdx.x;
    const int lane = tid & 63, wv = tid >> 6;
    const int wr = wv >> 1, wc = wv & 1;
    const int quad = lane >> 4, r = lane & 15;
    const int mb = blockIdx.y * 64, nb = blockIdx.x * 64;

    f32x4 acc[2][2] = {};
    const int srow = tid >> 2, skq = (tid & 3) * 8;
    const int wbase = (tid & 192) * 8;
    const bf16* APs[3] = {A0, A0, A1};
    const bf16* BPs[3] = {B0, B1, B0};
#pragma unroll
    for (int seg = 0; seg < 3; seg++) {
        const bf16* Ap = APs[seg];
        const bf16* Bp = BPs[seg];
        for (int k0 = 0; k0 < K; k0 += 32) {
            glds16(Ap + (long long)(mb + srow) * lda + k0 + skq, As + wbase);
            glds16(Bp + (long long)(nb + srow) * ldb + k0 + skq, Bs + wbase);
            __syncthreads();
            short8 b0 = *(const short8*)&Bs[(wc * 32 +  0 + r) * 32 + quad * 8];
            short8 b1 = *(const short8*)&Bs[(wc * 32 + 16 + r) * 32 + quad * 8];
#pragma unroll
            for (int mi = 0; mi < 2; mi++) {
                short8 afr = *(const short8*)&As[(wr * 32 + mi * 16 + r) * 32 + quad * 8];
                acc[mi][0] = __builtin_amdgcn_mfma_f32_16x16x32_bf16(afr, b0, acc[mi][0], 0, 0, 0);
                acc[mi][1] = __builtin_amdgcn_mfma_f32_16x16x32_bf16(afr, b1, acc[mi][1], 0, 0, 0);
            }
            __syncthreads();
        }
    }
#pragma unroll
    for (int mi = 0; mi < 2; mi++)
#pragma unroll
        for (int ni = 0; ni < 2; ni++) {
            int row0 = mb + wr * 32 + mi * 16 + quad * 4;
            int col = nb + wc * 32 + ni * 16 + r;
#pragma unroll
            for (int rr = 0; rr < 4; rr++) {
                long long ci = (long long)(row0 + rr) * ldc + col;
                Cf[ci] = FIRST ? acc[mi][ni][rr] : (Cf[ci] + acc[mi][ni][rr]);
            }
        }
}

// ---------------------------------------------------------------------------
// Round-4 64x64 core (VGPR staging, B [k][n]) — kept for a-GEMM and readout.
// EPI=0 store fp32 (ACC optional); TRIK=1 limits K to mb+64 (causal E rows).
template <int TRIK, int ACC, typename CT>
__global__ __launch_bounds__(256) void gemm3(
    const bf16* __restrict__ Ah, const bf16* __restrict__ Al, int lda, long long az,
    const bf16* __restrict__ Bh, const bf16* __restrict__ Bl, int ldb, long long bz,
    CT* __restrict__ Cf, int ldc, long long cz, int K) {
    __shared__ __align__(16) short Ash[64 * 40];
    __shared__ __align__(16) short Asl[64 * 40];
    __shared__ __align__(16) short Bsh[64 * 40];
    __shared__ __align__(16) short Bsl[64 * 40];
    const int tid = threadIdx.x;
    const int lane = tid & 63, wv = tid >> 6;
    const int wr = wv >> 1, wc = wv & 1;
    const int quad = lane >> 4, r = lane & 15;
    const int mb = blockIdx.y * 64, nb = blockIdx.x * 64;
    Ah += (long long)blockIdx.z * az; Al += (long long)blockIdx.z * az;
    Bh += (long long)blockIdx.z * bz; Bl += (long long)blockIdx.z * bz;
    Cf += (long long)blockIdx.z * cz;

    f32x4 acc[2][2] = {};
    const int ar = tid >> 2, ak = (tid & 3) * 8;
    const int bk = tid >> 3, bn = (tid & 7) * 8;
    const int Klim = TRIK ? (mb + 64) : K;
    for (int k0 = 0; k0 < Klim; k0 += 32) {
        *(short8*)&Ash[ar * 40 + ak] = *(const short8*)(Ah + (long long)(mb + ar) * lda + k0 + ak);
        *(short8*)&Asl[ar * 40 + ak] = *(const short8*)(Al + (long long)(mb + ar) * lda + k0 + ak);
        short8 bh = *(const short8*)(Bh + (long long)(k0 + bk) * ldb + nb + bn);
        short8 bl = *(const short8*)(Bl + (long long)(k0 + bk) * ldb + nb + bn);
#pragma unroll
        for (int j = 0; j < 8; j++) {
            Bsh[(bn + j) * 40 + bk] = bh[j];
            Bsl[(bn + j) * 40 + bk] = bl[j];
        }
        __syncthreads();
        short8 bh0 = *(const short8*)&Bsh[(wc * 32 +  0 + r) * 40 + quad * 8];
        short8 bl0 = *(const short8*)&Bsl[(wc * 32 +  0 + r) * 40 + quad * 8];
        short8 bh1 = *(const short8*)&Bsh[(wc * 32 + 16 + r) * 40 + quad * 8];
        short8 bl1 = *(const short8*)&Bsl[(wc * 32 + 16 + r) * 40 + quad * 8];
#pragma unroll
        for (int mi = 0; mi < 2; mi++) {
            short8 ah = *(const short8*)&Ash[(wr * 32 + mi * 16 + r) * 40 + quad * 8];
            short8 al = *(const short8*)&Asl[(wr * 32 + mi * 16 + r) * 40 + quad * 8];
            acc[mi][0] = __builtin_amdgcn_mfma_f32_16x16x32_bf16(ah, bh0, acc[mi][0], 0, 0, 0);
            acc[mi][0] = __builtin_amdgcn_mfma_f32_16x16x32_bf16(ah, bl0, acc[mi][0], 0, 0, 0);
            acc[mi][0] = __builtin_amdgcn_mfma_f32_16x16x32_bf16(al, bh0, acc[mi][0], 0, 0, 0);
            acc[mi][1] = __builtin_amdgcn_mfma_f32_16x16x32_bf16(ah, bh1, acc[mi][1], 0, 0, 0);
            acc[mi][1] = __builtin_amdgcn_mfma_f32_16x16x32_bf16(ah, bl1, acc[mi][1], 0, 0, 0);
            acc[mi][1] = __builtin_amdgcn_mfma_f32_16x16x32_bf16(al, bh1, acc[mi][1], 0, 0, 0);
        }
        __syncthreads();
    }
#pragma unroll
    for (int mi = 0; mi < 2; mi++)
#pragma unroll
        for (int ni = 0; ni < 2; ni++) {
            int row0 = mb + wr * 32 + mi * 16 + quad * 4;
            int col = nb + wc * 32 + ni * 16 + r;
#pragma unroll
            for (int rr = 0; rr < 4; rr++) {
                long long ci = (long long)(row0 + rr) * ldc + col;
                float val = acc[mi][ni][rr];
                Cf[ci] = ACC ? (CT)((float)Cf[ci] + val) : (CT)val;
            }
        }
}

// ---------------------------------------------------------------------------
extern "C" void kernel_launch(void* const* d_in, const int* in_sizes, int n_in,
                              void* d_out, int out_size, void* d_ws, size_t ws_size,
                              hipStream_t stream) {
    (void)in_sizes; (void)n_in; (void)out_size; (void)ws_size;
    const int* idx = (const int*)d_in[0];
    float* out = (float*)d_out;

    char* ws = (char*)d_ws;
    float* v32  = (float*)(ws);                    //  8 MiB
    bf16*  vh   = (bf16*)(ws + ( 8ll << 20));      //  4
    bf16*  vl   = (bf16*)(ws + (12ll << 20));      //  4
    bf16*  qh   = (bf16*)(ws + (16ll << 20));      //  4
    bf16*  ql   = (bf16*)(ws + (20ll << 20));      //  4
    float* a32  = (float*)(ws + (24ll << 20));     //  8  (aliases upd)
    float* upd  = a32;
    bf16*  lnh  = (bf16*)(ws + (32ll << 20));      //  4
    bf16*  lnl  = (bf16*)(ws + (36ll << 20));      //  4
    // union region 40..72 MiB: E pair (2 batches) during attention, x/y pair after
    bf16*  Eh   = (bf16*)(ws + (40ll << 20));      // 16 [2][2048][2048]
    bf16*  El   = (bf16*)(ws + (56ll << 20));      // 16
    bf16*  xh   = (bf16*)(ws + (40ll << 20));      // 16 [8192][1024]
    bf16*  xl   = (bf16*)(ws + (56ll << 20));      // 16
    bf16*  dxTh = (bf16*)(ws + (72ll << 20));      //  4 [H][M][D]
    bf16*  dxTl = (bf16*)(ws + (76ll << 20));      //  4
    bf16*  dyTh = (bf16*)(ws + (80ll << 20));      //  4
    bf16*  dyTl = (bf16*)(ws + (84ll << 20));      //  4
    bf16*  eTh  = (bf16*)(ws + (88ll << 20));      //  4 [256][8192]
    bf16*  eTl  = (bf16*)(ws + (92ll << 20));      //  4
    bf16*  roh  = (bf16*)(ws + (96ll << 20));      //  128 KiB
    bf16*  rol  = (bf16*)(ws + (96ll << 20) + (128ll << 10));
    int*   flag = (int*)(ws + (97ll << 20));
    // total ~97 MiB

    sniff_kernel<<<1, 256, 0, stream>>>((const unsigned short*)d_in[1], flag);
    // weights: transpose + hi/lo split (dx,dy per head: [D][M]->[M][D]; enc: [N][D]->[D][N])
    tr_split_kernel<<<dim3(MHk / 32, Dk / 32, 4), 256, 0, stream>>>(
        d_in[3], flag, dxTh, dxTl, Dk, MHk, (long long)Dk * MHk, (long long)Dk * MHk);
    tr_split_kernel<<<dim3(MHk / 32, Dk / 32, 4), 256, 0, stream>>>(
        d_in[4], flag, dyTh, dyTl, Dk, MHk, (long long)Dk * MHk, (long long)Dk * MHk);
    tr_split_kernel<<<dim3(Dk / 32, 8192 / 32, 1), 256, 0, stream>>>(
        d_in[2], flag, eTh, eTl, 8192, Dk, 0, 0);
    cvt_split_kernel<<<256, 256, 0, stream>>>(d_in[5], flag, roh, rol, Dk * 256);

    embed_ln_kernel<<<BTk, 256, 0, stream>>>(idx, d_in[1], flag, v32, vh, vl);

    for (int l = 0; l < LAYERS; l++) {
        rope_kernel<<<BTk, 128, 0, stream>>>(v32, qh, ql);
        for (int half = 0; half < 2; half++) {
            const long long qo = (long long)half * 2 * Tk * Dk;
            // E = tril(Qr Qr^T): 2 batches per launch, hi/lo out
            gemm128<0><<<dim3(Tk / 128, Tk / 128, 2), 256, 0, stream>>>(
                qh + qo, ql + qo, Dk, (long long)Tk * Dk,
                qh + qo, ql + qo, Dk, (long long)Tk * Dk,
                Eh, El, Tk, (long long)Tk * Tk, Dk);
            // a = E @ v (fp32), K limited per row-block (causal)
            gemm3<1, 0, float><<<dim3(Dk / 64, Tk / 64, 2), 256, 0, stream>>>(
                Eh, El, Tk, (long long)Tk * Tk,
                vh + qo, vl + qo, Dk, (long long)Tk * Dk,
                a32 + qo, Dk, (long long)Tk * Dk, Tk);
        }
        ln_rows_kernel<<<BTk, 256, 0, stream>>>(a32, lnh, lnl);
        bool first = true;
        for (int h = 0; h < 4; h++) {
            for (int c = 0; c < MHk / CHk; c++) {
                const long long wofs = ((long long)h * MHk + c * CHk) * Dk;  // rows of [M][D]
                const long long kofs = (long long)h * MHk + c * CHk;         // k-offset in enc^T
                // x = relu(v @ dx_h)  -> (xh,xl)
                gemm128<1><<<dim3(CHk / 128, BTk / 128, 1), 256, 0, stream>>>(
                    vh, vl, Dk, 0, dxTh + wofs, dxTl + wofs, Dk, 0,
                    xh, xl, CHk, 0, Dk);
                // y = relu(ln(a) @ dy_h) * x -> overwrite (xh,xl)
                gemm128<2><<<dim3(CHk / 128, BTk / 128, 1), 256, 0, stream>>>(
                    lnh, lnl, Dk, 0, dyTh + wofs, dyTl + wofs, Dk, 0,
                    xh, xl, CHk, 0, Dk);
                // upd (+)= y @ enc_chunk
                if (first) {
                    gemm64u<1><<<dim3(Dk / 64, BTk / 64), 256, 0, stream>>>(
                        xh, xl, CHk, eTh + kofs, eTl + kofs, 8192, upd, Dk, CHk);
                    first = false;
                } else {
                    gemm64u<0><<<dim3(Dk / 64, BTk / 64), 256, 0, stream>>>(
                        xh, xl, CHk, eTh + kofs, eTl + kofs, 8192, upd, Dk, CHk);
                }
            }
        }
        add_ln_kernel<<<BTk, 256, 0, stream>>>(upd, v32, vh, vl);
    }
    // logits = v @ readout (fp32 out)
    gemm3<0, 0, float><<<dim3(256 / 64, BTk / 64, 1), 256, 0, stream>>>(
        vh, vl, Dk, 0, roh, rol, 256, 0, out, 256, 0, Dk);
}

// Round 6
// 3448.002 us; speedup vs baseline: 2.8001x; 2.0120x over previous
//
#include <hip/hip_runtime.h>
#include <hip/hip_bf16.h>

typedef __hip_bfloat16 bf16;
typedef _Float16 half_t;
typedef __attribute__((ext_vector_type(8))) short short8;
typedef __attribute__((ext_vector_type(8))) _Float16 half8;
typedef __attribute__((ext_vector_type(4))) float f32x4;

#define LN_EPS 1e-5f

static constexpr int Dk     = 256;   // model dim
static constexpr int Tk     = 2048;  // seq len
static constexpr int BTk    = 8192;  // B*T
static constexpr int MHk    = 2048;  // N/H
static constexpr int LAYERS = 6;
static constexpr long long TD   = (long long)Tk * Dk;      // 524288
static constexpr long long BTD  = (long long)BTk * Dk;     // 2097152

// ---------------------------------------------------------------------------
__device__ __forceinline__ float wave_reduce(float v) {
#pragma unroll
    for (int o = 32; o > 0; o >>= 1) v += __shfl_down(v, o);
    return v;
}

__device__ __forceinline__ float block_sum_256(float x, float* sbuf) {
    float s = wave_reduce(x);
    int lane = threadIdx.x & 63, wv = threadIdx.x >> 6;
    if (lane == 0) sbuf[wv] = s;
    __syncthreads();
    float r = sbuf[0] + sbuf[1] + sbuf[2] + sbuf[3];
    __syncthreads();
    return r;
}

__device__ __forceinline__ void split_bf16(float x, bf16* h, bf16* l) {
    bf16 hh = (bf16)x;
    *h = hh;
    *l = (bf16)(x - (float)hh);
}

// async global->LDS, 16B/lane; LDS base wave-uniform, HW appends lane*16.
__device__ __forceinline__ void glds16(const void* g, void* lds) {
    __builtin_amdgcn_global_load_lds(
        (const __attribute__((address_space(1))) void*)g,
        (__attribute__((address_space(3))) void*)lds, 16, 0, 0);
}

// ---------------------------------------------------------------------------
// input dtype sniffer (insurance; inputs confirmed fp32)
__global__ __launch_bounds__(256) void sniff_kernel(const unsigned short* __restrict__ w,
                                                    int* __restrict__ flag) {
    __shared__ float sbuf[4];
    int tid = threadIdx.x;
    float cnt = 0.f;
    for (int i = tid; i < 1024; i += 256) {
        int e = (w[i] >> 7) & 0xFF;
        if (e >= 128) cnt += 1.f;
    }
    float tot = block_sum_256(cnt, sbuf);
    if (tid == 0) *flag = (tot > 32.f) ? 1 : 0;
}

// transpose + fp16 convert: src [R][C] (per z) -> dst [C][R] fp16
__global__ __launch_bounds__(256) void tr_cvt16_kernel(const void* __restrict__ src,
                                                       const int* __restrict__ flag,
                                                       half_t* __restrict__ dst,
                                                       int R, int C,
                                                       long long sz, long long dz) {
    __shared__ float t[32][33];
    bool f32 = (*flag != 0);
    int ct = blockIdx.x * 32, rt = blockIdx.y * 32;
    long long so = (long long)blockIdx.z * sz, dofs = (long long)blockIdx.z * dz;
    int tx = threadIdx.x & 31, ty = threadIdx.x >> 5;
#pragma unroll
    for (int i = 0; i < 4; i++) {
        long long idx = so + (long long)(rt + ty + i * 8) * C + ct + tx;
        t[ty + i * 8][tx] = f32 ? ((const float*)src)[idx] : (float)((const bf16*)src)[idx];
    }
    __syncthreads();
#pragma unroll
    for (int i = 0; i < 4; i++) {
        long long odx = dofs + (long long)(ct + ty + i * 8) * R + rt + tx;
        dst[odx] = (half_t)t[tx][ty + i * 8];
    }
}

// ---------------------------------------------------------------------------
// v = layernorm(wte[idx]) -> v32 fp32, vf fp16, (vh,vl) bf16 pair
__global__ __launch_bounds__(256) void embed_ln_kernel(const int* __restrict__ idx,
                                                       const void* __restrict__ wte,
                                                       const int* __restrict__ flag,
                                                       float* __restrict__ v,
                                                       half_t* __restrict__ vf,
                                                       bf16* __restrict__ vh,
                                                       bf16* __restrict__ vl) {
    __shared__ float sbuf[4];
    int bt = blockIdx.x, tid = threadIdx.x;
    int id = idx[bt];
    bool f32 = (*flag != 0);
    float x = f32 ? ((const float*)wte)[id * Dk + tid]
                  : (float)((const bf16*)wte)[id * Dk + tid];
    float mu = block_sum_256(x, sbuf) * (1.f / 256.f);
    float d = x - mu;
    float var = block_sum_256(d * d, sbuf) * (1.f / 256.f);
    float r = d * rsqrtf(var + LN_EPS);
    v[bt * Dk + tid] = r;
    vf[bt * Dk + tid] = (half_t)r;
    split_bf16(r, &vh[bt * Dk + tid], &vl[bt * Dk + tid]);
}

// lnf = fp16(layernorm(a32))
__global__ __launch_bounds__(256) void ln_rows_kernel(const float* __restrict__ a,
                                                      half_t* __restrict__ of) {
    __shared__ float sbuf[4];
    int bt = blockIdx.x, tid = threadIdx.x;
    float x = a[bt * Dk + tid];
    float mu = block_sum_256(x, sbuf) * (1.f / 256.f);
    float d = x - mu;
    float var = block_sum_256(d * d, sbuf) * (1.f / 256.f);
    float r = d * rsqrtf(var + LN_EPS);
    of[bt * Dk + tid] = (half_t)r;
}

// v += layernorm(upd) -> refresh v32, vf, (vh,vl)
__global__ __launch_bounds__(256) void add_ln_kernel(const float* __restrict__ upd,
                                                     float* __restrict__ v,
                                                     half_t* __restrict__ vf,
                                                     bf16* __restrict__ vh,
                                                     bf16* __restrict__ vl) {
    __shared__ float sbuf[4];
    int bt = blockIdx.x, tid = threadIdx.x;
    float x = upd[bt * Dk + tid];
    float mu = block_sum_256(x, sbuf) * (1.f / 256.f);
    float d = x - mu;
    float var = block_sum_256(d * d, sbuf) * (1.f / 256.f);
    float r = d * rsqrtf(var + LN_EPS);
    float nv = v[bt * Dk + tid] + r;
    v[bt * Dk + tid] = nv;
    vf[bt * Dk + tid] = (half_t)nv;
    split_bf16(nv, &vh[bt * Dk + tid], &vl[bt * Dk + tid]);
}

// RoPE from fp32 v -> (qh,ql) bf16 pair (Q == K)
__global__ __launch_bounds__(128) void rope_kernel(const float* __restrict__ v,
                                                   bf16* __restrict__ qh,
                                                   bf16* __restrict__ ql) {
    int bt = blockIdx.x, i = threadIdx.x;
    int t = bt & (Tk - 1);
    float invf = powf(10000.f, -(float)i / 128.f);
    float ang = (float)t * invf;
    float s, c;
    sincosf(ang, &s, &c);
    float q1 = v[bt * Dk + i];
    float q2 = v[bt * Dk + 128 + i];
    split_bf16(q1 * c - q2 * s, &qh[bt * Dk + i],       &ql[bt * Dk + i]);
    split_bf16(q2 * c + q1 * s, &qh[bt * Dk + 128 + i], &ql[bt * Dk + 128 + i]);
}

// ---------------------------------------------------------------------------
// Energy: 128x128 bf16 async GEMM, 3 K-segments compensation.
// A,B [rows][K] row-major; causal mask, store hi/lo bf16; above-diag zero-fill.
__global__ __launch_bounds__(256) void gemm128e(
    const bf16* __restrict__ A0, const bf16* __restrict__ A1, int lda, long long az,
    const bf16* __restrict__ B0, const bf16* __restrict__ B1, int ldb, long long bz,
    bf16* __restrict__ Ch, bf16* __restrict__ Cl, int ldc, long long cz, int K) {
    __shared__ __align__(16) bf16 As[128 * 32];
    __shared__ __align__(16) bf16 Bs[128 * 32];
    const int tid = threadIdx.x;
    const int lane = tid & 63, wv = tid >> 6;
    const int wr = wv >> 1, wc = wv & 1;
    const int quad = lane >> 4, r = lane & 15;
    const int mb = blockIdx.y * 128, nb = blockIdx.x * 128;
    A0 += (long long)blockIdx.z * az; A1 += (long long)blockIdx.z * az;
    B0 += (long long)blockIdx.z * bz; B1 += (long long)blockIdx.z * bz;
    Ch += (long long)blockIdx.z * cz; Cl += (long long)blockIdx.z * cz;

    if ((int)blockIdx.x > (int)blockIdx.y) {
#pragma unroll
        for (int e = 0; e < 64; e++) {
            int ii = e * 256 + tid;
            long long ci = (long long)(mb + (ii >> 7)) * ldc + nb + (ii & 127);
            Ch[ci] = (bf16)0.f;
            Cl[ci] = (bf16)0.f;
        }
        return;
    }

    f32x4 acc[4][4] = {};
    const int srow = tid >> 2, skq = (tid & 3) * 8;
    const int wbase = (tid & 192) * 8;
    const bf16* APs[3] = {A0, A0, A1};
    const bf16* BPs[3] = {B0, B1, B0};
#pragma unroll
    for (int seg = 0; seg < 3; seg++) {
        const bf16* Ap = APs[seg];
        const bf16* Bp = BPs[seg];
        for (int k0 = 0; k0 < K; k0 += 32) {
#pragma unroll
            for (int rnd = 0; rnd < 2; rnd++) {
                int row = rnd * 64 + srow;
                glds16(Ap + (long long)(mb + row) * lda + k0 + skq, As + rnd * 2048 + wbase);
                glds16(Bp + (long long)(nb + row) * ldb + k0 + skq, Bs + rnd * 2048 + wbase);
            }
            __syncthreads();
            short8 bfr[4];
#pragma unroll
            for (int ni = 0; ni < 4; ni++)
                bfr[ni] = *(const short8*)&Bs[(wc * 64 + ni * 16 + r) * 32 + quad * 8];
#pragma unroll
            for (int mi = 0; mi < 4; mi++) {
                short8 afr = *(const short8*)&As[(wr * 64 + mi * 16 + r) * 32 + quad * 8];
#pragma unroll
                for (int ni = 0; ni < 4; ni++)
                    acc[mi][ni] = __builtin_amdgcn_mfma_f32_16x16x32_bf16(afr, bfr[ni], acc[mi][ni], 0, 0, 0);
            }
            __syncthreads();
        }
    }
#pragma unroll
    for (int mi = 0; mi < 4; mi++)
#pragma unroll
        for (int ni = 0; ni < 4; ni++) {
            int row0 = mb + wr * 64 + mi * 16 + quad * 4;
            int col = nb + wc * 64 + ni * 16 + r;
#pragma unroll
            for (int rr = 0; rr < 4; rr++) {
                int row = row0 + rr;
                long long ci = (long long)row * ldc + col;
                float val = acc[mi][ni][rr];
                if (row < col) val = 0.f;
                bf16 h, l;
                split_bf16(val, &h, &l);
                Ch[ci] = h;
                Cl[ci] = l;
            }
        }
}

// ---------------------------------------------------------------------------
// a-GEMM split-K: P[z] = E_chunk @ V, compensated bf16, 64x64 tile.
// z = b2*4 + c; b2 = local batch (of 2), c = K-chunk of 512.
// E [b2][T][T] (zeros above diag), V (vh,vl) [b2][T][D]. Causal: K limited
// to mb+64; chunks fully beyond zero-fill their P tile.
__global__ __launch_bounds__(256) void gemm3a(
    const bf16* __restrict__ Eh, const bf16* __restrict__ El,
    const bf16* __restrict__ Vh, const bf16* __restrict__ Vl,
    float* __restrict__ P) {
    __shared__ __align__(16) short Ash[64 * 40];
    __shared__ __align__(16) short Asl[64 * 40];
    __shared__ __align__(16) short Bsh[64 * 40];
    __shared__ __align__(16) short Bsl[64 * 40];
    const int tid = threadIdx.x;
    const int lane = tid & 63, wv = tid >> 6;
    const int wr = wv >> 1, wc = wv & 1;
    const int quad = lane >> 4, r = lane & 15;
    const int mb = blockIdx.y * 64, nb = blockIdx.x * 64;
    const int b2 = blockIdx.z >> 2, c = blockIdx.z & 3;
    const bf16* Ah = Eh + (long long)b2 * Tk * Tk;
    const bf16* Al = El + (long long)b2 * Tk * Tk;
    const bf16* Bh = Vh + (long long)b2 * TD;
    const bf16* Bl = Vl + (long long)b2 * TD;
    float* Pc = P + (long long)blockIdx.z * TD;

    const int kbeg = c * 512;
    const int kend = min(mb + 64, kbeg + 512);
    if (kend <= kbeg) {
#pragma unroll
        for (int e = 0; e < 16; e++) {
            int ii = e * 256 + tid;
            Pc[(long long)(mb + (ii >> 6)) * Dk + nb + (ii & 63)] = 0.f;
        }
        return;
    }

    f32x4 acc[2][2] = {};
    const int ar = tid >> 2, ak = (tid & 3) * 8;
    const int bk = tid >> 3, bn = (tid & 7) * 8;
    for (int k0 = kbeg; k0 < kend; k0 += 32) {
        *(short8*)&Ash[ar * 40 + ak] = *(const short8*)(Ah + (long long)(mb + ar) * Tk + k0 + ak);
        *(short8*)&Asl[ar * 40 + ak] = *(const short8*)(Al + (long long)(mb + ar) * Tk + k0 + ak);
        short8 bh = *(const short8*)(Bh + (long long)(k0 + bk) * Dk + nb + bn);
        short8 bl = *(const short8*)(Bl + (long long)(k0 + bk) * Dk + nb + bn);
#pragma unroll
        for (int j = 0; j < 8; j++) {
            Bsh[(bn + j) * 40 + bk] = bh[j];
            Bsl[(bn + j) * 40 + bk] = bl[j];
        }
        __syncthreads();
        short8 bh0 = *(const short8*)&Bsh[(wc * 32 +  0 + r) * 40 + quad * 8];
        short8 bl0 = *(const short8*)&Bsl[(wc * 32 +  0 + r) * 40 + quad * 8];
        short8 bh1 = *(const short8*)&Bsh[(wc * 32 + 16 + r) * 40 + quad * 8];
        short8 bl1 = *(const short8*)&Bsl[(wc * 32 + 16 + r) * 40 + quad * 8];
#pragma unroll
        for (int mi = 0; mi < 2; mi++) {
            short8 ah = *(const short8*)&Ash[(wr * 32 + mi * 16 + r) * 40 + quad * 8];
            short8 al = *(const short8*)&Asl[(wr * 32 + mi * 16 + r) * 40 + quad * 8];
            acc[mi][0] = __builtin_amdgcn_mfma_f32_16x16x32_bf16(ah, bh0, acc[mi][0], 0, 0, 0);
            acc[mi][0] = __builtin_amdgcn_mfma_f32_16x16x32_bf16(ah, bl0, acc[mi][0], 0, 0, 0);
            acc[mi][0] = __builtin_amdgcn_mfma_f32_16x16x32_bf16(al, bh0, acc[mi][0], 0, 0, 0);
            acc[mi][1] = __builtin_amdgcn_mfma_f32_16x16x32_bf16(ah, bh1, acc[mi][1], 0, 0, 0);
            acc[mi][1] = __builtin_amdgcn_mfma_f32_16x16x32_bf16(ah, bl1, acc[mi][1], 0, 0, 0);
            acc[mi][1] = __builtin_amdgcn_mfma_f32_16x16x32_bf16(al, bh1, acc[mi][1], 0, 0, 0);
        }
        __syncthreads();
    }
#pragma unroll
    for (int mi = 0; mi < 2; mi++)
#pragma unroll
        for (int ni = 0; ni < 2; ni++) {
            int row0 = mb + wr * 32 + mi * 16 + quad * 4;
            int col = nb + wc * 32 + ni * 16 + r;
#pragma unroll
            for (int rr = 0; rr < 4; rr++)
                Pc[(long long)(row0 + rr) * Dk + col] = acc[mi][ni][rr];
        }
}

// a32[half] = sum of 4 K-chunk partials
__global__ __launch_bounds__(256) void reduce_a_kernel(const float* __restrict__ P,
                                                       float* __restrict__ aout) {
    long long e = (long long)blockIdx.x * 256 + threadIdx.x;   // < 2*TD
    long long b = e >> 19, i = e & (TD - 1);
    const float* p = P + b * 4 * TD + i;
    aout[e] = p[0] + p[TD] + p[2 * TD] + p[3 * TD];
}

// ---------------------------------------------------------------------------
// fp16 128x128 async GEMM. A [M][K], B [N][K] fp16.
// EPI 1: store relu(acc) fp16; EPI 2: store relu(acc)*C fp16 (RMW).
template <int EPI>
__global__ __launch_bounds__(256) void gemm128h(
    const half_t* __restrict__ A, int lda,
    const half_t* __restrict__ B, int ldb,
    half_t* __restrict__ C, int ldc, int K) {
    __shared__ __align__(16) half_t As[128 * 32];
    __shared__ __align__(16) half_t Bs[128 * 32];
    const int tid = threadIdx.x;
    const int lane = tid & 63, wv = tid >> 6;
    const int wr = wv >> 1, wc = wv & 1;
    const int quad = lane >> 4, r = lane & 15;
    const int mb = blockIdx.y * 128, nb = blockIdx.x * 128;

    f32x4 acc[4][4] = {};
    const int srow = tid >> 2, skq = (tid & 3) * 8;
    const int wbase = (tid & 192) * 8;
    for (int k0 = 0; k0 < K; k0 += 32) {
#pragma unroll
        for (int rnd = 0; rnd < 2; rnd++) {
            int row = rnd * 64 + srow;
            glds16(A + (long long)(mb + row) * lda + k0 + skq, As + rnd * 2048 + wbase);
            glds16(B + (long long)(nb + row) * ldb + k0 + skq, Bs + rnd * 2048 + wbase);
        }
        __syncthreads();
        half8 bfr[4];
#pragma unroll
        for (int ni = 0; ni < 4; ni++)
            bfr[ni] = *(const half8*)&Bs[(wc * 64 + ni * 16 + r) * 32 + quad * 8];
#pragma unroll
        for (int mi = 0; mi < 4; mi++) {
            half8 afr = *(const half8*)&As[(wr * 64 + mi * 16 + r) * 32 + quad * 8];
#pragma unroll
            for (int ni = 0; ni < 4; ni++)
                acc[mi][ni] = __builtin_amdgcn_mfma_f32_16x16x32_f16(afr, bfr[ni], acc[mi][ni], 0, 0, 0);
        }
        __syncthreads();
    }
#pragma unroll
    for (int mi = 0; mi < 4; mi++)
#pragma unroll
        for (int ni = 0; ni < 4; ni++) {
            int row0 = mb + wr * 64 + mi * 16 + quad * 4;
            int col = nb + wc * 64 + ni * 16 + r;
#pragma unroll
            for (int rr = 0; rr < 4; rr++) {
                long long ci = (long long)(row0 + rr) * ldc + col;
                float val = fmaxf(acc[mi][ni][rr], 0.f);
                if (EPI == 2) val *= (float)C[ci];
                C[ci] = (half_t)val;
            }
        }
}

// ---------------------------------------------------------------------------
// fp16 64x64 async GEMM, fp32 store. A [M][K], B [N][K]; z advances the
// K-window by kofs and the output by cofs (split-K partials / plain store).
__global__ __launch_bounds__(256) void gemm64h(
    const half_t* __restrict__ A, int lda,
    const half_t* __restrict__ B, int ldb,
    float* __restrict__ C, int ldc,
    int kofs, long long cofs, int K) {
    __shared__ __align__(16) half_t As[64 * 32];
    __shared__ __align__(16) half_t Bs[64 * 32];
    const int tid = threadIdx.x;
    const int lane = tid & 63, wv = tid >> 6;
    const int wr = wv >> 1, wc = wv & 1;
    const int quad = lane >> 4, r = lane & 15;
    const int mb = blockIdx.y * 64, nb = blockIdx.x * 64;
    A += (long long)blockIdx.z * kofs;
    B += (long long)blockIdx.z * kofs;
    C += (long long)blockIdx.z * cofs;

    f32x4 acc[2][2] = {};
    const int srow = tid >> 2, skq = (tid & 3) * 8;
    const int wbase = (tid & 192) * 8;
    for (int k0 = 0; k0 < K; k0 += 32) {
        glds16(A + (long long)(mb + srow) * lda + k0 + skq, As + wbase);
        glds16(B + (long long)(nb + srow) * ldb + k0 + skq, Bs + wbase);
        __syncthreads();
        half8 b0 = *(const half8*)&Bs[(wc * 32 +  0 + r) * 32 + quad * 8];
        half8 b1 = *(const half8*)&Bs[(wc * 32 + 16 + r) * 32 + quad * 8];
#pragma unroll
        for (int mi = 0; mi < 2; mi++) {
            half8 afr = *(const half8*)&As[(wr * 32 + mi * 16 + r) * 32 + quad * 8];
            acc[mi][0] = __builtin_amdgcn_mfma_f32_16x16x32_f16(afr, b0, acc[mi][0], 0, 0, 0);
            acc[mi][1] = __builtin_amdgcn_mfma_f32_16x16x32_f16(afr, b1, acc[mi][1], 0, 0, 0);
        }
        __syncthreads();
    }
#pragma unroll
    for (int mi = 0; mi < 2; mi++)
#pragma unroll
        for (int ni = 0; ni < 2; ni++) {
            int row0 = mb + wr * 32 + mi * 16 + quad * 4;
            int col = nb + wc * 32 + ni * 16 + r;
#pragma unroll
            for (int rr = 0; rr < 4; rr++)
                C[(long long)(row0 + rr) * ldc + col] = acc[mi][ni][rr];
        }
}

// upd (=|+=) P[0] + P[1]
template <int FIRST>
__global__ __launch_bounds__(256) void reduce_u_kernel(const float* __restrict__ P,
                                                       float* __restrict__ upd) {
    long long e = (long long)blockIdx.x * 256 + threadIdx.x;
    float s = P[e] + P[e + BTD];
    upd[e] = FIRST ? s : (upd[e] + s);
}

// ---------------------------------------------------------------------------
extern "C" void kernel_launch(void* const* d_in, const int* in_sizes, int n_in,
                              void* d_out, int out_size, void* d_ws, size_t ws_size,
                              hipStream_t stream) {
    (void)in_sizes; (void)n_in; (void)out_size; (void)ws_size;
    const int* idx = (const int*)d_in[0];
    float* out = (float*)d_out;

    char* ws = (char*)d_ws;
    float*  v32  = (float*) (ws);                   //  8 MiB [8192][256]
    half_t* vf   = (half_t*)(ws + ( 8ll << 20));    //  4
    bf16*   vh   = (bf16*)  (ws + (12ll << 20));    //  4
    bf16*   vl   = (bf16*)  (ws + (16ll << 20));    //  4
    bf16*   qh   = (bf16*)  (ws + (20ll << 20));    //  4
    bf16*   ql   = (bf16*)  (ws + (24ll << 20));    //  4
    float*  a32  = (float*) (ws + (28ll << 20));    //  8
    half_t* lnf  = (half_t*)(ws + (36ll << 20));    //  4
    float*  upd  = (float*) (ws + (40ll << 20));    //  8
    // region 48..80 MiB: attention E pair (2 batches) / decoder x fp16
    bf16*   Eh   = (bf16*)  (ws + (48ll << 20));    // 16 [2][2048][2048]
    bf16*   El   = (bf16*)  (ws + (64ll << 20));    // 16
    half_t* x16  = (half_t*)(ws + (48ll << 20));    // 32 [8192][2048]
    // region 80..96 MiB: attention Pa [8][2048][256] / decoder Pu [2][8192][256]
    float*  Pa   = (float*) (ws + (80ll << 20));    // 16
    float*  Pu   = (float*) (ws + (80ll << 20));    // 16
    half_t* dxT  = (half_t*)(ws + (96ll << 20));    //  4 [H][M][D] fp16
    half_t* dyT  = (half_t*)(ws + (100ll << 20));   //  4
    half_t* eT   = (half_t*)(ws + (104ll << 20));   //  4 [256][8192] fp16
    half_t* roT  = (half_t*)(ws + (108ll << 20));   //  128 KiB [256][256]
    int*    flag = (int*)   (ws + (108ll << 20) + (256ll << 10));
    // total ~108.3 MiB

    sniff_kernel<<<1, 256, 0, stream>>>((const unsigned short*)d_in[1], flag);
    tr_cvt16_kernel<<<dim3(MHk / 32, Dk / 32, 4), 256, 0, stream>>>(
        d_in[3], flag, dxT, Dk, MHk, (long long)Dk * MHk, (long long)Dk * MHk);
    tr_cvt16_kernel<<<dim3(MHk / 32, Dk / 32, 4), 256, 0, stream>>>(
        d_in[4], flag, dyT, Dk, MHk, (long long)Dk * MHk, (long long)Dk * MHk);
    tr_cvt16_kernel<<<dim3(Dk / 32, 8192 / 32, 1), 256, 0, stream>>>(
        d_in[2], flag, eT, 8192, Dk, 0, 0);
    tr_cvt16_kernel<<<dim3(Dk / 32, Dk / 32, 1), 256, 0, stream>>>(
        d_in[5], flag, roT, Dk, Dk, 0, 0);

    embed_ln_kernel<<<BTk, 256, 0, stream>>>(idx, d_in[1], flag, v32, vf, vh, vl);

    for (int l = 0; l < LAYERS; l++) {
        rope_kernel<<<BTk, 128, 0, stream>>>(v32, qh, ql);
        for (int half = 0; half < 2; half++) {
            const long long qo = (long long)half * 2 * TD;
            // E = tril(Qr Qr^T), compensated, hi/lo pair, 2 batches
            gemm128e<<<dim3(Tk / 128, Tk / 128, 2), 256, 0, stream>>>(
                qh + qo, ql + qo, Dk, TD,
                qh + qo, ql + qo, Dk, TD,
                Eh, El, Tk, (long long)Tk * Tk, Dk);
            // a partials: split-K x4 over causal K, 2 batches -> Pa[8][T][D]
            gemm3a<<<dim3(Dk / 64, Tk / 64, 8), 256, 0, stream>>>(
                Eh, El, vh + qo, vl + qo, Pa);
            reduce_a_kernel<<<2 * TD / 256, 256, 0, stream>>>(Pa, a32 + qo);
        }
        ln_rows_kernel<<<BTk, 256, 0, stream>>>(a32, lnf);
        for (int h = 0; h < 4; h++) {
            const long long wofs = (long long)h * MHk * Dk;  // head rows of [M][D]
            // x = relu(vf @ dx_h^T)
            gemm128h<1><<<dim3(MHk / 128, BTk / 128), 256, 0, stream>>>(
                vf, Dk, dxT + wofs, Dk, x16, MHk, Dk);
            // y = relu(lnf @ dy_h^T) * x  (in place)
            gemm128h<2><<<dim3(MHk / 128, BTk / 128), 256, 0, stream>>>(
                lnf, Dk, dyT + wofs, Dk, x16, MHk, Dk);
            // Pu[z] = y[:, z*1024 : z*1024+1024] @ enc_chunk
            gemm64h<<<dim3(Dk / 64, BTk / 64, 2), 256, 0, stream>>>(
                x16, MHk, eT + (long long)h * MHk, 8192,
                Pu, Dk, 1024, BTD, 1024);
            if (h == 0)
                reduce_u_kernel<1><<<BTD / 256, 256, 0, stream>>>(Pu, upd);
            else
                reduce_u_kernel<0><<<BTD / 256, 256, 0, stream>>>(Pu, upd);
        }
        add_ln_kernel<<<BTk, 256, 0, stream>>>(upd, v32, vf, vh, vl);
    }
    // logits = vf @ roT^T -> fp32 out
    gemm64h<<<dim3(Dk / 64, BTk / 64, 1), 256, 0, stream>>>(
        vf, Dk, roT, Dk, out, Dk, 0, 0, Dk);
}

// Round 7
// 2481.958 us; speedup vs baseline: 3.8899x; 1.3892x over previous
//
#include <hip/hip_runtime.h>
#include <hip/hip_bf16.h>

typedef __hip_bfloat16 bf16;
typedef _Float16 half_t;
typedef __attribute__((ext_vector_type(8))) _Float16 half8;
typedef __attribute__((ext_vector_type(4))) float f32x4;

#define LN_EPS 1e-5f

static constexpr int Dk     = 256;   // model dim
static constexpr int Tk     = 2048;  // seq len
static constexpr int BTk    = 8192;  // B*T
static constexpr int MHk    = 2048;  // N/H
static constexpr int LAYERS = 6;
static constexpr long long TD  = (long long)Tk * Dk;    // 524288
static constexpr long long BTD = (long long)BTk * Dk;   // 2097152
static constexpr long long TT  = (long long)Tk * Tk;    // 4194304

// ---------------------------------------------------------------------------
__device__ __forceinline__ float wave_reduce(float v) {
#pragma unroll
    for (int o = 32; o > 0; o >>= 1) v += __shfl_down(v, o);
    return v;
}

__device__ __forceinline__ float block_sum_256(float x, float* sbuf) {
    float s = wave_reduce(x);
    int lane = threadIdx.x & 63, wv = threadIdx.x >> 6;
    if (lane == 0) sbuf[wv] = s;
    __syncthreads();
    float r = sbuf[0] + sbuf[1] + sbuf[2] + sbuf[3];
    __syncthreads();
    return r;
}

// async global->LDS, 16B/lane; LDS base wave-uniform, HW appends lane*16.
__device__ __forceinline__ void glds16(const void* g, void* lds) {
    __builtin_amdgcn_global_load_lds(
        (const __attribute__((address_space(1))) void*)g,
        (__attribute__((address_space(3))) void*)lds, 16, 0, 0);
}

// ---------------------------------------------------------------------------
// input dtype sniffer (insurance; inputs confirmed fp32)
__global__ __launch_bounds__(256) void sniff_kernel(const unsigned short* __restrict__ w,
                                                    int* __restrict__ flag) {
    __shared__ float sbuf[4];
    int tid = threadIdx.x;
    float cnt = 0.f;
    for (int i = tid; i < 1024; i += 256) {
        int e = (w[i] >> 7) & 0xFF;
        if (e >= 128) cnt += 1.f;
    }
    float tot = block_sum_256(cnt, sbuf);
    if (tid == 0) *flag = (tot > 32.f) ? 1 : 0;
}

// transpose + fp16 convert: src [R][C] (per z) -> dst [C][R] fp16
__global__ __launch_bounds__(256) void tr_cvt16_kernel(const void* __restrict__ src,
                                                       const int* __restrict__ flag,
                                                       half_t* __restrict__ dst,
                                                       int R, int C,
                                                       long long sz, long long dz) {
    __shared__ float t[32][33];
    bool f32 = (*flag != 0);
    int ct = blockIdx.x * 32, rt = blockIdx.y * 32;
    long long so = (long long)blockIdx.z * sz, dofs = (long long)blockIdx.z * dz;
    int tx = threadIdx.x & 31, ty = threadIdx.x >> 5;
#pragma unroll
    for (int i = 0; i < 4; i++) {
        long long idx = so + (long long)(rt + ty + i * 8) * C + ct + tx;
        t[ty + i * 8][tx] = f32 ? ((const float*)src)[idx] : (float)((const bf16*)src)[idx];
    }
    __syncthreads();
#pragma unroll
    for (int i = 0; i < 4; i++) {
        long long odx = dofs + (long long)(ct + ty + i * 8) * R + rt + tx;
        dst[odx] = (half_t)t[tx][ty + i * 8];
    }
}

// v32 [BT][D] fp32 -> vT [D][BT] fp16
__global__ __launch_bounds__(256) void trv_kernel(const float* __restrict__ src,
                                                  half_t* __restrict__ dst) {
    __shared__ float t[32][33];
    int ct = blockIdx.x * 32, rt = blockIdx.y * 32;
    int tx = threadIdx.x & 31, ty = threadIdx.x >> 5;
#pragma unroll
    for (int i = 0; i < 4; i++)
        t[ty + i * 8][tx] = src[(long long)(rt + ty + i * 8) * Dk + ct + tx];
    __syncthreads();
#pragma unroll
    for (int i = 0; i < 4; i++)
        dst[(long long)(ct + ty + i * 8) * BTk + rt + tx] = (half_t)t[tx][ty + i * 8];
}

// ---------------------------------------------------------------------------
// v = layernorm(wte[idx]) -> v32 fp32, vf fp16
__global__ __launch_bounds__(256) void embed_ln_kernel(const int* __restrict__ idx,
                                                       const void* __restrict__ wte,
                                                       const int* __restrict__ flag,
                                                       float* __restrict__ v,
                                                       half_t* __restrict__ vf) {
    __shared__ float sbuf[4];
    int bt = blockIdx.x, tid = threadIdx.x;
    int id = idx[bt];
    bool f32 = (*flag != 0);
    float x = f32 ? ((const float*)wte)[id * Dk + tid]
                  : (float)((const bf16*)wte)[id * Dk + tid];
    float mu = block_sum_256(x, sbuf) * (1.f / 256.f);
    float d = x - mu;
    float var = block_sum_256(d * d, sbuf) * (1.f / 256.f);
    float r = d * rsqrtf(var + LN_EPS);
    v[bt * Dk + tid] = r;
    vf[bt * Dk + tid] = (half_t)r;
}

// lnf = fp16(layernorm(a32))
__global__ __launch_bounds__(256) void ln_rows_kernel(const float* __restrict__ a,
                                                      half_t* __restrict__ of) {
    __shared__ float sbuf[4];
    int bt = blockIdx.x, tid = threadIdx.x;
    float x = a[bt * Dk + tid];
    float mu = block_sum_256(x, sbuf) * (1.f / 256.f);
    float d = x - mu;
    float var = block_sum_256(d * d, sbuf) * (1.f / 256.f);
    float r = d * rsqrtf(var + LN_EPS);
    of[bt * Dk + tid] = (half_t)r;
}

// v += layernorm(upd) -> refresh v32, vf
__global__ __launch_bounds__(256) void add_ln_kernel(const float* __restrict__ upd,
                                                     float* __restrict__ v,
                                                     half_t* __restrict__ vf) {
    __shared__ float sbuf[4];
    int bt = blockIdx.x, tid = threadIdx.x;
    float x = upd[bt * Dk + tid];
    float mu = block_sum_256(x, sbuf) * (1.f / 256.f);
    float d = x - mu;
    float var = block_sum_256(d * d, sbuf) * (1.f / 256.f);
    float r = d * rsqrtf(var + LN_EPS);
    float nv = v[bt * Dk + tid] + r;
    v[bt * Dk + tid] = nv;
    vf[bt * Dk + tid] = (half_t)nv;
}

// RoPE from fp32 v -> qf fp16 (Q == K)
__global__ __launch_bounds__(128) void rope_kernel(const float* __restrict__ v,
                                                   half_t* __restrict__ qf) {
    int bt = blockIdx.x, i = threadIdx.x;
    int t = bt & (Tk - 1);
    float invf = powf(10000.f, -(float)i / 128.f);
    float ang = (float)t * invf;
    float s, c;
    sincosf(ang, &s, &c);
    float q1 = v[bt * Dk + i];
    float q2 = v[bt * Dk + 128 + i];
    qf[bt * Dk + i]       = (half_t)(q1 * c - q2 * s);
    qf[bt * Dk + 128 + i] = (half_t)(q2 * c + q1 * s);
}

// ---------------------------------------------------------------------------
// Energy: E[b] = tril(Qr Qr^T), fp16, 128x128 async GEMM, z = batch.
__global__ __launch_bounds__(256) void gemm128e(
    const half_t* __restrict__ Q, half_t* __restrict__ E) {
    __shared__ __align__(16) half_t As[128 * 32];
    __shared__ __align__(16) half_t Bs[128 * 32];
    const int tid = threadIdx.x;
    const int lane = tid & 63, wv = tid >> 6;
    const int wr = wv >> 1, wc = wv & 1;
    const int quad = lane >> 4, r = lane & 15;
    const int mb = blockIdx.y * 128, nb = blockIdx.x * 128;
    const half_t* Qb = Q + (long long)blockIdx.z * TD;
    half_t* Eb = E + (long long)blockIdx.z * TT;

    if ((int)blockIdx.x > (int)blockIdx.y) {
#pragma unroll
        for (int e = 0; e < 64; e++) {
            int ii = e * 256 + tid;
            Eb[(long long)(mb + (ii >> 7)) * Tk + nb + (ii & 127)] = (half_t)0.f;
        }
        return;
    }

    f32x4 acc[4][4] = {};
    const int srow = tid >> 2, skq = (tid & 3) * 8;
    const int wbase = (tid & 192) * 8;
    for (int k0 = 0; k0 < Dk; k0 += 32) {
#pragma unroll
        for (int rnd = 0; rnd < 2; rnd++) {
            int row = rnd * 64 + srow;
            glds16(Qb + (long long)(mb + row) * Dk + k0 + skq, As + rnd * 2048 + wbase);
            glds16(Qb + (long long)(nb + row) * Dk + k0 + skq, Bs + rnd * 2048 + wbase);
        }
        __syncthreads();
        half8 bfr[4];
#pragma unroll
        for (int ni = 0; ni < 4; ni++)
            bfr[ni] = *(const half8*)&Bs[(wc * 64 + ni * 16 + r) * 32 + quad * 8];
#pragma unroll
        for (int mi = 0; mi < 4; mi++) {
            half8 afr = *(const half8*)&As[(wr * 64 + mi * 16 + r) * 32 + quad * 8];
#pragma unroll
            for (int ni = 0; ni < 4; ni++)
                acc[mi][ni] = __builtin_amdgcn_mfma_f32_16x16x32_f16(afr, bfr[ni], acc[mi][ni], 0, 0, 0);
        }
        __syncthreads();
    }
#pragma unroll
    for (int mi = 0; mi < 4; mi++)
#pragma unroll
        for (int ni = 0; ni < 4; ni++) {
            int row0 = mb + wr * 64 + mi * 16 + quad * 4;
            int col = nb + wc * 64 + ni * 16 + r;
#pragma unroll
            for (int rr = 0; rr < 4; rr++) {
                int row = row0 + rr;
                float val = (row < col) ? 0.f : acc[mi][ni][rr];
                Eb[(long long)row * Tk + col] = (half_t)val;
            }
        }
}

// ---------------------------------------------------------------------------
// a-GEMM split-K atomic: a32 += E_chunk @ V. z = b*4 + c (b batch, c K-chunk
// of 512). A=E[b] [T][T]; B=vT [D][BT] col-window b*T. Causal: kend=min(mb+64,
// kbeg+512); empty chunks return (a32 pre-zeroed by memset).
__global__ __launch_bounds__(256) void gemm64a(
    const half_t* __restrict__ E, const half_t* __restrict__ vT,
    float* __restrict__ a32) {
    __shared__ __align__(16) half_t As[64 * 32];
    __shared__ __align__(16) half_t Bs[64 * 32];
    const int tid = threadIdx.x;
    const int lane = tid & 63, wv = tid >> 6;
    const int wr = wv >> 1, wc = wv & 1;
    const int quad = lane >> 4, r = lane & 15;
    const int mb = blockIdx.y * 64, nb = blockIdx.x * 64;
    const int b = blockIdx.z >> 2, c = blockIdx.z & 3;
    const int kbeg = c * 512;
    const int kend = min(mb + 64, kbeg + 512);
    if (kend <= kbeg) return;

    const half_t* Ab = E + (long long)b * TT;
    const half_t* Bb = vT + (long long)b * Tk;   // column offset into [D][BT]
    f32x4 acc[2][2] = {};
    const int srow = tid >> 2, skq = (tid & 3) * 8;
    const int wbase = (tid & 192) * 8;
    for (int k0 = kbeg; k0 < kend; k0 += 32) {
        glds16(Ab + (long long)(mb + srow) * Tk + k0 + skq, As + wbase);
        glds16(Bb + (long long)(nb + srow) * BTk + k0 + skq, Bs + wbase);
        __syncthreads();
        half8 b0 = *(const half8*)&Bs[(wc * 32 +  0 + r) * 32 + quad * 8];
        half8 b1 = *(const half8*)&Bs[(wc * 32 + 16 + r) * 32 + quad * 8];
#pragma unroll
        for (int mi = 0; mi < 2; mi++) {
            half8 afr = *(const half8*)&As[(wr * 32 + mi * 16 + r) * 32 + quad * 8];
            acc[mi][0] = __builtin_amdgcn_mfma_f32_16x16x32_f16(afr, b0, acc[mi][0], 0, 0, 0);
            acc[mi][1] = __builtin_amdgcn_mfma_f32_16x16x32_f16(afr, b1, acc[mi][1], 0, 0, 0);
        }
        __syncthreads();
    }
#pragma unroll
    for (int mi = 0; mi < 2; mi++)
#pragma unroll
        for (int ni = 0; ni < 2; ni++) {
            int row0 = mb + wr * 32 + mi * 16 + quad * 4;
            int col = nb + wc * 32 + ni * 16 + r;
#pragma unroll
            for (int rr = 0; rr < 4; rr++)
                atomicAdd(&a32[(long long)(b * Tk + row0 + rr) * Dk + col], acc[mi][ni][rr]);
        }
}

// ---------------------------------------------------------------------------
// Fused dual fp16 GEMM, 128x64 tile:
//   y = relu(lnf @ dyT_h) * relu(vf @ dxT_h), fp16 out [BT][M].
__global__ __launch_bounds__(256) void dual_gemm(
    const half_t* __restrict__ A1,   // vf  [BT][D]
    const half_t* __restrict__ A2,   // lnf [BT][D]
    const half_t* __restrict__ B1,   // dxT head base [M][D]
    const half_t* __restrict__ B2,   // dyT head base [M][D]
    half_t* __restrict__ C) {
    __shared__ __align__(16) half_t As1[128 * 32];
    __shared__ __align__(16) half_t As2[128 * 32];
    __shared__ __align__(16) half_t Bs1[64 * 32];
    __shared__ __align__(16) half_t Bs2[64 * 32];
    const int tid = threadIdx.x;
    const int lane = tid & 63, wv = tid >> 6;
    const int wr = wv >> 1, wc = wv & 1;
    const int quad = lane >> 4, r = lane & 15;
    const int mb = blockIdx.y * 128, nb = blockIdx.x * 64;

    f32x4 accX[4][2] = {};
    f32x4 accY[4][2] = {};
    const int srow = tid >> 2, skq = (tid & 3) * 8;
    const int wbase = (tid & 192) * 8;
    for (int k0 = 0; k0 < Dk; k0 += 32) {
        glds16(A1 + (long long)(mb + srow) * Dk + k0 + skq, As1 + wbase);
        glds16(A1 + (long long)(mb + 64 + srow) * Dk + k0 + skq, As1 + 2048 + wbase);
        glds16(A2 + (long long)(mb + srow) * Dk + k0 + skq, As2 + wbase);
        glds16(A2 + (long long)(mb + 64 + srow) * Dk + k0 + skq, As2 + 2048 + wbase);
        glds16(B1 + (long long)(nb + srow) * Dk + k0 + skq, Bs1 + wbase);
        glds16(B2 + (long long)(nb + srow) * Dk + k0 + skq, Bs2 + wbase);
        __syncthreads();
        half8 b1f[2], b2f[2];
#pragma unroll
        for (int ni = 0; ni < 2; ni++) {
            b1f[ni] = *(const half8*)&Bs1[(wc * 32 + ni * 16 + r) * 32 + quad * 8];
            b2f[ni] = *(const half8*)&Bs2[(wc * 32 + ni * 16 + r) * 32 + quad * 8];
        }
#pragma unroll
        for (int mi = 0; mi < 4; mi++) {
            half8 a1 = *(const half8*)&As1[(wr * 64 + mi * 16 + r) * 32 + quad * 8];
            half8 a2 = *(const half8*)&As2[(wr * 64 + mi * 16 + r) * 32 + quad * 8];
#pragma unroll
            for (int ni = 0; ni < 2; ni++) {
                accX[mi][ni] = __builtin_amdgcn_mfma_f32_16x16x32_f16(a1, b1f[ni], accX[mi][ni], 0, 0, 0);
                accY[mi][ni] = __builtin_amdgcn_mfma_f32_16x16x32_f16(a2, b2f[ni], accY[mi][ni], 0, 0, 0);
            }
        }
        __syncthreads();
    }
#pragma unroll
    for (int mi = 0; mi < 4; mi++)
#pragma unroll
        for (int ni = 0; ni < 2; ni++) {
            int row0 = mb + wr * 64 + mi * 16 + quad * 4;
            int col = nb + wc * 32 + ni * 16 + r;
#pragma unroll
            for (int rr = 0; rr < 4; rr++) {
                float val = fmaxf(accY[mi][ni][rr], 0.f) * fmaxf(accX[mi][ni][rr], 0.f);
                C[(long long)(row0 + rr) * MHk + col] = (half_t)val;
            }
        }
}

// ---------------------------------------------------------------------------
// Update split-K atomic: upd += y @ enc_h. A=y16 [BT][M], B=eT head window
// [D][8192]. z = K-chunk of 512 (4 chunks over M=2048).
__global__ __launch_bounds__(256) void gemm64u_at(
    const half_t* __restrict__ A, const half_t* __restrict__ B,
    float* __restrict__ upd) {
    __shared__ __align__(16) half_t As[64 * 32];
    __shared__ __align__(16) half_t Bs[64 * 32];
    const int tid = threadIdx.x;
    const int lane = tid & 63, wv = tid >> 6;
    const int wr = wv >> 1, wc = wv & 1;
    const int quad = lane >> 4, r = lane & 15;
    const int mb = blockIdx.y * 64, nb = blockIdx.x * 64;
    const int kbeg = blockIdx.z * 512;

    f32x4 acc[2][2] = {};
    const int srow = tid >> 2, skq = (tid & 3) * 8;
    const int wbase = (tid & 192) * 8;
    for (int k0 = kbeg; k0 < kbeg + 512; k0 += 32) {
        glds16(A + (long long)(mb + srow) * MHk + k0 + skq, As + wbase);
        glds16(B + (long long)(nb + srow) * BTk + k0 + skq, Bs + wbase);
        __syncthreads();
        half8 b0 = *(const half8*)&Bs[(wc * 32 +  0 + r) * 32 + quad * 8];
        half8 b1 = *(const half8*)&Bs[(wc * 32 + 16 + r) * 32 + quad * 8];
#pragma unroll
        for (int mi = 0; mi < 2; mi++) {
            half8 afr = *(const half8*)&As[(wr * 32 + mi * 16 + r) * 32 + quad * 8];
            acc[mi][0] = __builtin_amdgcn_mfma_f32_16x16x32_f16(afr, b0, acc[mi][0], 0, 0, 0);
            acc[mi][1] = __builtin_amdgcn_mfma_f32_16x16x32_f16(afr, b1, acc[mi][1], 0, 0, 0);
        }
        __syncthreads();
    }
#pragma unroll
    for (int mi = 0; mi < 2; mi++)
#pragma unroll
        for (int ni = 0; ni < 2; ni++) {
            int row0 = mb + wr * 32 + mi * 16 + quad * 4;
            int col = nb + wc * 32 + ni * 16 + r;
#pragma unroll
            for (int rr = 0; rr < 4; rr++)
                atomicAdd(&upd[(long long)(row0 + rr) * Dk + col], acc[mi][ni][rr]);
        }
}

// ---------------------------------------------------------------------------
// Plain fp16 64x64 async GEMM, fp32 store — readout. A [M][K], B [N][K].
__global__ __launch_bounds__(256) void gemm64h(
    const half_t* __restrict__ A, int lda,
    const half_t* __restrict__ B, int ldb,
    float* __restrict__ C, int ldc, int K) {
    __shared__ __align__(16) half_t As[64 * 32];
    __shared__ __align__(16) half_t Bs[64 * 32];
    const int tid = threadIdx.x;
    const int lane = tid & 63, wv = tid >> 6;
    const int wr = wv >> 1, wc = wv & 1;
    const int quad = lane >> 4, r = lane & 15;
    const int mb = blockIdx.y * 64, nb = blockIdx.x * 64;

    f32x4 acc[2][2] = {};
    const int srow = tid >> 2, skq = (tid & 3) * 8;
    const int wbase = (tid & 192) * 8;
    for (int k0 = 0; k0 < K; k0 += 32) {
        glds16(A + (long long)(mb + srow) * lda + k0 + skq, As + wbase);
        glds16(B + (long long)(nb + srow) * ldb + k0 + skq, Bs + wbase);
        __syncthreads();
        half8 b0 = *(const half8*)&Bs[(wc * 32 +  0 + r) * 32 + quad * 8];
        half8 b1 = *(const half8*)&Bs[(wc * 32 + 16 + r) * 32 + quad * 8];
#pragma unroll
        for (int mi = 0; mi < 2; mi++) {
            half8 afr = *(const half8*)&As[(wr * 32 + mi * 16 + r) * 32 + quad * 8];
            acc[mi][0] = __builtin_amdgcn_mfma_f32_16x16x32_f16(afr, b0, acc[mi][0], 0, 0, 0);
            acc[mi][1] = __builtin_amdgcn_mfma_f32_16x16x32_f16(afr, b1, acc[mi][1], 0, 0, 0);
        }
        __syncthreads();
    }
#pragma unroll
    for (int mi = 0; mi < 2; mi++)
#pragma unroll
        for (int ni = 0; ni < 2; ni++) {
            int row0 = mb + wr * 32 + mi * 16 + quad * 4;
            int col = nb + wc * 32 + ni * 16 + r;
#pragma unroll
            for (int rr = 0; rr < 4; rr++)
                C[(long long)(row0 + rr) * ldc + col] = acc[mi][ni][rr];
        }
}

// ---------------------------------------------------------------------------
extern "C" void kernel_launch(void* const* d_in, const int* in_sizes, int n_in,
                              void* d_out, int out_size, void* d_ws, size_t ws_size,
                              hipStream_t stream) {
    (void)in_sizes; (void)n_in; (void)out_size; (void)ws_size;
    const int* idx = (const int*)d_in[0];
    float* out = (float*)d_out;

    char* ws = (char*)d_ws;
    float*  v32  = (float*) (ws);                   //  8 MiB [8192][256]
    half_t* vf   = (half_t*)(ws + ( 8ll << 20));    //  4
    half_t* qf   = (half_t*)(ws + (12ll << 20));    //  4
    half_t* vT   = (half_t*)(ws + (16ll << 20));    //  4 [256][8192]
    float*  a32  = (float*) (ws + (20ll << 20));    //  8 (alias upd: phase-disjoint)
    float*  upd  = a32;
    half_t* lnf  = (half_t*)(ws + (28ll << 20));    //  4
    half_t* E    = (half_t*)(ws + (32ll << 20));    // 32 [4][2048][2048] f16
    half_t* y16  = (half_t*)(ws + (64ll << 20));    // 32 [8192][2048] f16
    half_t* dxT  = (half_t*)(ws + (96ll << 20));    //  4 [H][M][D]
    half_t* dyT  = (half_t*)(ws + (100ll << 20));   //  4
    half_t* eT   = (half_t*)(ws + (104ll << 20));   //  4 [256][8192]
    half_t* roT  = (half_t*)(ws + (108ll << 20));   //  128 KiB [256][256]
    int*    flag = (int*)   (ws + (108ll << 20) + (256ll << 10));
    // total ~108.3 MiB (== round-6 proven footprint)

    sniff_kernel<<<1, 256, 0, stream>>>((const unsigned short*)d_in[1], flag);
    tr_cvt16_kernel<<<dim3(MHk / 32, Dk / 32, 4), 256, 0, stream>>>(
        d_in[3], flag, dxT, Dk, MHk, (long long)Dk * MHk, (long long)Dk * MHk);
    tr_cvt16_kernel<<<dim3(MHk / 32, Dk / 32, 4), 256, 0, stream>>>(
        d_in[4], flag, dyT, Dk, MHk, (long long)Dk * MHk, (long long)Dk * MHk);
    tr_cvt16_kernel<<<dim3(Dk / 32, BTk / 32, 1), 256, 0, stream>>>(
        d_in[2], flag, eT, BTk, Dk, 0, 0);
    tr_cvt16_kernel<<<dim3(Dk / 32, Dk / 32, 1), 256, 0, stream>>>(
        d_in[5], flag, roT, Dk, Dk, 0, 0);

    embed_ln_kernel<<<BTk, 256, 0, stream>>>(idx, d_in[1], flag, v32, vf);

    for (int l = 0; l < LAYERS; l++) {
        rope_kernel<<<BTk, 128, 0, stream>>>(v32, qf);
        trv_kernel<<<dim3(Dk / 32, BTk / 32), 256, 0, stream>>>(v32, vT);
        // E[b] = tril(Qr Qr^T), fp16, all 4 batches
        gemm128e<<<dim3(Tk / 128, Tk / 128, 4), 256, 0, stream>>>(qf, E);
        // a32 = E @ v via split-K atomics (pre-zeroed)
        hipMemsetAsync(a32, 0, BTD * sizeof(float), stream);
        gemm64a<<<dim3(Dk / 64, Tk / 64, 16), 256, 0, stream>>>(E, vT, a32);
        ln_rows_kernel<<<BTk, 256, 0, stream>>>(a32, lnf);
        // decoder: per head, fused dual GEMM then split-K atomic update
        hipMemsetAsync(upd, 0, BTD * sizeof(float), stream);
        for (int h = 0; h < 4; h++) {
            const long long wofs = (long long)h * MHk * Dk;
            dual_gemm<<<dim3(MHk / 64, BTk / 128), 256, 0, stream>>>(
                vf, lnf, dxT + wofs, dyT + wofs, y16);
            gemm64u_at<<<dim3(Dk / 64, BTk / 64, 4), 256, 0, stream>>>(
                y16, eT + (long long)h * MHk, upd);
        }
        add_ln_kernel<<<BTk, 256, 0, stream>>>(upd, v32, vf);
    }
    // logits = vf @ roT^T -> fp32 out
    gemm64h<<<dim3(Dk / 64, BTk / 64), 256, 0, stream>>>(
        vf, Dk, roT, Dk, out, Dk, Dk);
}

// Round 8
// 2228.308 us; speedup vs baseline: 4.3327x; 1.1138x over previous
//
#include <hip/hip_runtime.h>
#include <hip/hip_bf16.h>

typedef __hip_bfloat16 bf16;
typedef _Float16 half_t;
typedef __attribute__((ext_vector_type(8))) _Float16 half8;
typedef __attribute__((ext_vector_type(4))) float f32x4;

#define LN_EPS 1e-5f

static constexpr int Dk     = 256;   // model dim
static constexpr int Tk     = 2048;  // seq len
static constexpr int BTk    = 8192;  // B*T
static constexpr int MHk    = 2048;  // N/H
static constexpr int LAYERS = 6;
static constexpr long long TD  = (long long)Tk * Dk;    // 524288
static constexpr long long BTD = (long long)BTk * Dk;   // 2097152
static constexpr long long TT  = (long long)Tk * Tk;    // 4194304

// ---------------------------------------------------------------------------
__device__ __forceinline__ float wave_reduce(float v) {
#pragma unroll
    for (int o = 32; o > 0; o >>= 1) v += __shfl_down(v, o);
    return v;
}

__device__ __forceinline__ float block_sum_256(float x, float* sbuf) {
    float s = wave_reduce(x);
    int lane = threadIdx.x & 63, wv = threadIdx.x >> 6;
    if (lane == 0) sbuf[wv] = s;
    __syncthreads();
    float r = sbuf[0] + sbuf[1] + sbuf[2] + sbuf[3];
    __syncthreads();
    return r;
}

// async global->LDS, 16B/lane; LDS base wave-uniform, HW appends lane*16.
__device__ __forceinline__ void glds16(const void* g, void* lds) {
    __builtin_amdgcn_global_load_lds(
        (const __attribute__((address_space(1))) void*)g,
        (__attribute__((address_space(3))) void*)lds, 16, 0, 0);
}

// ---------------------------------------------------------------------------
// input dtype sniffer (insurance; inputs confirmed fp32)
__global__ __launch_bounds__(256) void sniff_kernel(const unsigned short* __restrict__ w,
                                                    int* __restrict__ flag) {
    __shared__ float sbuf[4];
    int tid = threadIdx.x;
    float cnt = 0.f;
    for (int i = tid; i < 1024; i += 256) {
        int e = (w[i] >> 7) & 0xFF;
        if (e >= 128) cnt += 1.f;
    }
    float tot = block_sum_256(cnt, sbuf);
    if (tid == 0) *flag = (tot > 32.f) ? 1 : 0;
}

// transpose + fp16 convert: src [R][C] (per z) -> dst [C][R] fp16
__global__ __launch_bounds__(256) void tr_cvt16_kernel(const void* __restrict__ src,
                                                       const int* __restrict__ flag,
                                                       half_t* __restrict__ dst,
                                                       int R, int C,
                                                       long long sz, long long dz) {
    __shared__ float t[32][33];
    bool f32 = (*flag != 0);
    int ct = blockIdx.x * 32, rt = blockIdx.y * 32;
    long long so = (long long)blockIdx.z * sz, dofs = (long long)blockIdx.z * dz;
    int tx = threadIdx.x & 31, ty = threadIdx.x >> 5;
#pragma unroll
    for (int i = 0; i < 4; i++) {
        long long idx = so + (long long)(rt + ty + i * 8) * C + ct + tx;
        t[ty + i * 8][tx] = f32 ? ((const float*)src)[idx] : (float)((const bf16*)src)[idx];
    }
    __syncthreads();
#pragma unroll
    for (int i = 0; i < 4; i++) {
        long long odx = dofs + (long long)(ct + ty + i * 8) * R + rt + tx;
        dst[odx] = (half_t)t[tx][ty + i * 8];
    }
}

// v32 [BT][D] fp32 -> vT [D][BT] fp16
__global__ __launch_bounds__(256) void trv_kernel(const float* __restrict__ src,
                                                  half_t* __restrict__ dst) {
    __shared__ float t[32][33];
    int ct = blockIdx.x * 32, rt = blockIdx.y * 32;
    int tx = threadIdx.x & 31, ty = threadIdx.x >> 5;
#pragma unroll
    for (int i = 0; i < 4; i++)
        t[ty + i * 8][tx] = src[(long long)(rt + ty + i * 8) * Dk + ct + tx];
    __syncthreads();
#pragma unroll
    for (int i = 0; i < 4; i++)
        dst[(long long)(ct + ty + i * 8) * BTk + rt + tx] = (half_t)t[tx][ty + i * 8];
}

// ---------------------------------------------------------------------------
// v = layernorm(wte[idx]) -> v32 fp32, vf fp16
__global__ __launch_bounds__(256) void embed_ln_kernel(const int* __restrict__ idx,
                                                       const void* __restrict__ wte,
                                                       const int* __restrict__ flag,
                                                       float* __restrict__ v,
                                                       half_t* __restrict__ vf) {
    __shared__ float sbuf[4];
    int bt = blockIdx.x, tid = threadIdx.x;
    int id = idx[bt];
    bool f32 = (*flag != 0);
    float x = f32 ? ((const float*)wte)[id * Dk + tid]
                  : (float)((const bf16*)wte)[id * Dk + tid];
    float mu = block_sum_256(x, sbuf) * (1.f / 256.f);
    float d = x - mu;
    float var = block_sum_256(d * d, sbuf) * (1.f / 256.f);
    float r = d * rsqrtf(var + LN_EPS);
    v[bt * Dk + tid] = r;
    vf[bt * Dk + tid] = (half_t)r;
}

// lnf = fp16(layernorm(a32))
__global__ __launch_bounds__(256) void ln_rows_kernel(const float* __restrict__ a,
                                                      half_t* __restrict__ of) {
    __shared__ float sbuf[4];
    int bt = blockIdx.x, tid = threadIdx.x;
    float x = a[bt * Dk + tid];
    float mu = block_sum_256(x, sbuf) * (1.f / 256.f);
    float d = x - mu;
    float var = block_sum_256(d * d, sbuf) * (1.f / 256.f);
    float r = d * rsqrtf(var + LN_EPS);
    of[bt * Dk + tid] = (half_t)r;
}

// v += layernorm(upd) -> refresh v32, vf
__global__ __launch_bounds__(256) void add_ln_kernel(const float* __restrict__ upd,
                                                     float* __restrict__ v,
                                                     half_t* __restrict__ vf) {
    __shared__ float sbuf[4];
    int bt = blockIdx.x, tid = threadIdx.x;
    float x = upd[bt * Dk + tid];
    float mu = block_sum_256(x, sbuf) * (1.f / 256.f);
    float d = x - mu;
    float var = block_sum_256(d * d, sbuf) * (1.f / 256.f);
    float r = d * rsqrtf(var + LN_EPS);
    float nv = v[bt * Dk + tid] + r;
    v[bt * Dk + tid] = nv;
    vf[bt * Dk + tid] = (half_t)nv;
}

// RoPE from fp32 v -> qf fp16 (Q == K)
__global__ __launch_bounds__(128) void rope_kernel(const float* __restrict__ v,
                                                   half_t* __restrict__ qf) {
    int bt = blockIdx.x, i = threadIdx.x;
    int t = bt & (Tk - 1);
    float invf = powf(10000.f, -(float)i / 128.f);
    float ang = (float)t * invf;
    float s, c;
    sincosf(ang, &s, &c);
    float q1 = v[bt * Dk + i];
    float q2 = v[bt * Dk + 128 + i];
    qf[bt * Dk + i]       = (half_t)(q1 * c - q2 * s);
    qf[bt * Dk + 128 + i] = (half_t)(q2 * c + q1 * s);
}

// ---------------------------------------------------------------------------
// Energy: E[b] = tril(Qr Qr^T), fp16, 128x128 async GEMM, z = batch.
__global__ __launch_bounds__(256) void gemm128e(
    const half_t* __restrict__ Q, half_t* __restrict__ E) {
    __shared__ __align__(16) half_t As[128 * 32];
    __shared__ __align__(16) half_t Bs[128 * 32];
    const int tid = threadIdx.x;
    const int lane = tid & 63, wv = tid >> 6;
    const int wr = wv >> 1, wc = wv & 1;
    const int quad = lane >> 4, r = lane & 15;
    const int mb = blockIdx.y * 128, nb = blockIdx.x * 128;
    const half_t* Qb = Q + (long long)blockIdx.z * TD;
    half_t* Eb = E + (long long)blockIdx.z * TT;

    if ((int)blockIdx.x > (int)blockIdx.y) {
#pragma unroll
        for (int e = 0; e < 64; e++) {
            int ii = e * 256 + tid;
            Eb[(long long)(mb + (ii >> 7)) * Tk + nb + (ii & 127)] = (half_t)0.f;
        }
        return;
    }

    f32x4 acc[4][4] = {};
    const int srow = tid >> 2, skq = (tid & 3) * 8;
    const int wbase = (tid & 192) * 8;
    for (int k0 = 0; k0 < Dk; k0 += 32) {
#pragma unroll
        for (int rnd = 0; rnd < 2; rnd++) {
            int row = rnd * 64 + srow;
            glds16(Qb + (long long)(mb + row) * Dk + k0 + skq, As + rnd * 2048 + wbase);
            glds16(Qb + (long long)(nb + row) * Dk + k0 + skq, Bs + rnd * 2048 + wbase);
        }
        __syncthreads();
        half8 bfr[4];
#pragma unroll
        for (int ni = 0; ni < 4; ni++)
            bfr[ni] = *(const half8*)&Bs[(wc * 64 + ni * 16 + r) * 32 + quad * 8];
#pragma unroll
        for (int mi = 0; mi < 4; mi++) {
            half8 afr = *(const half8*)&As[(wr * 64 + mi * 16 + r) * 32 + quad * 8];
#pragma unroll
            for (int ni = 0; ni < 4; ni++)
                acc[mi][ni] = __builtin_amdgcn_mfma_f32_16x16x32_f16(afr, bfr[ni], acc[mi][ni], 0, 0, 0);
        }
        __syncthreads();
    }
#pragma unroll
    for (int mi = 0; mi < 4; mi++)
#pragma unroll
        for (int ni = 0; ni < 4; ni++) {
            int row0 = mb + wr * 64 + mi * 16 + quad * 4;
            int col = nb + wc * 64 + ni * 16 + r;
#pragma unroll
            for (int rr = 0; rr < 4; rr++) {
                int row = row0 + rr;
                float val = (row < col) ? 0.f : acc[mi][ni][rr];
                Eb[(long long)row * Tk + col] = (half_t)val;
            }
        }
}

// ---------------------------------------------------------------------------
// a-GEMM: a32 += E_chunk @ V, 128x128, split-K atomics.
// z = b*4 + c (batch, K-chunk of 512). A=E[b] [T][T]; B=vT [D][BT] window b*T.
// Causal: kend=min(mb+128, kbeg+512); dead chunks return (a32 pre-zeroed).
__global__ __launch_bounds__(256) void gemm128a(
    const half_t* __restrict__ E, const half_t* __restrict__ vT,
    float* __restrict__ a32) {
    __shared__ __align__(16) half_t As[128 * 32];
    __shared__ __align__(16) half_t Bs[128 * 32];
    const int tid = threadIdx.x;
    const int lane = tid & 63, wv = tid >> 6;
    const int wr = wv >> 1, wc = wv & 1;
    const int quad = lane >> 4, r = lane & 15;
    const int mb = blockIdx.y * 128, nb = blockIdx.x * 128;
    const int b = blockIdx.z >> 2, c = blockIdx.z & 3;
    const int kbeg = c * 512;
    const int kend = min(mb + 128, kbeg + 512);
    if (kend <= kbeg) return;

    const half_t* Ab = E + (long long)b * TT;
    const half_t* Bb = vT + (long long)b * Tk;
    f32x4 acc[4][4] = {};
    const int srow = tid >> 2, skq = (tid & 3) * 8;
    const int wbase = (tid & 192) * 8;
    for (int k0 = kbeg; k0 < kend; k0 += 32) {
#pragma unroll
        for (int rnd = 0; rnd < 2; rnd++) {
            int row = rnd * 64 + srow;
            glds16(Ab + (long long)(mb + row) * Tk + k0 + skq, As + rnd * 2048 + wbase);
            glds16(Bb + (long long)(nb + row) * BTk + k0 + skq, Bs + rnd * 2048 + wbase);
        }
        __syncthreads();
        half8 bfr[4];
#pragma unroll
        for (int ni = 0; ni < 4; ni++)
            bfr[ni] = *(const half8*)&Bs[(wc * 64 + ni * 16 + r) * 32 + quad * 8];
#pragma unroll
        for (int mi = 0; mi < 4; mi++) {
            half8 afr = *(const half8*)&As[(wr * 64 + mi * 16 + r) * 32 + quad * 8];
#pragma unroll
            for (int ni = 0; ni < 4; ni++)
                acc[mi][ni] = __builtin_amdgcn_mfma_f32_16x16x32_f16(afr, bfr[ni], acc[mi][ni], 0, 0, 0);
        }
        __syncthreads();
    }
#pragma unroll
    for (int mi = 0; mi < 4; mi++)
#pragma unroll
        for (int ni = 0; ni < 4; ni++) {
            int row0 = mb + wr * 64 + mi * 16 + quad * 4;
            int col = nb + wc * 64 + ni * 16 + r;
#pragma unroll
            for (int rr = 0; rr < 4; rr++)
                atomicAdd(&a32[(long long)(b * Tk + row0 + rr) * Dk + col], acc[mi][ni][rr]);
        }
}

// ---------------------------------------------------------------------------
// Fused dual fp16 GEMM, 512 threads (8 waves, 2x4), 128x128 tile:
//   y = relu(lnf @ dyT_h) * relu(vf @ dxT_h), fp16 out [BT][M].
__global__ __launch_bounds__(512) void dual_gemm(
    const half_t* __restrict__ A1,   // vf  [BT][D]
    const half_t* __restrict__ A2,   // lnf [BT][D]
    const half_t* __restrict__ B1,   // dxT head base [M][D]
    const half_t* __restrict__ B2,   // dyT head base [M][D]
    half_t* __restrict__ C) {
    __shared__ __align__(16) half_t As1[128 * 32];
    __shared__ __align__(16) half_t As2[128 * 32];
    __shared__ __align__(16) half_t Bs1[128 * 32];
    __shared__ __align__(16) half_t Bs2[128 * 32];
    const int tid = threadIdx.x;
    const int lane = tid & 63, wv = tid >> 6;     // 8 waves
    const int wr = wv >> 2, wc = wv & 3;          // 2 x 4 wave grid
    const int quad = lane >> 4, r = lane & 15;
    const int mb = blockIdx.y * 128, nb = blockIdx.x * 128;

    f32x4 accX[4][2] = {};
    f32x4 accY[4][2] = {};
    const int srow = tid >> 2, skq = (tid & 3) * 8;   // 512 thr: whole 128x32 tile per glds
    const int wbase = (tid & 448) * 8;                // wv * 512 elems
    for (int k0 = 0; k0 < Dk; k0 += 32) {
        glds16(A1 + (long long)(mb + srow) * Dk + k0 + skq, As1 + wbase);
        glds16(A2 + (long long)(mb + srow) * Dk + k0 + skq, As2 + wbase);
        glds16(B1 + (long long)(nb + srow) * Dk + k0 + skq, Bs1 + wbase);
        glds16(B2 + (long long)(nb + srow) * Dk + k0 + skq, Bs2 + wbase);
        __syncthreads();
        half8 b1f[2], b2f[2];
#pragma unroll
        for (int ni = 0; ni < 2; ni++) {
            b1f[ni] = *(const half8*)&Bs1[(wc * 32 + ni * 16 + r) * 32 + quad * 8];
            b2f[ni] = *(const half8*)&Bs2[(wc * 32 + ni * 16 + r) * 32 + quad * 8];
        }
#pragma unroll
        for (int mi = 0; mi < 4; mi++) {
            half8 a1 = *(const half8*)&As1[(wr * 64 + mi * 16 + r) * 32 + quad * 8];
            half8 a2 = *(const half8*)&As2[(wr * 64 + mi * 16 + r) * 32 + quad * 8];
#pragma unroll
            for (int ni = 0; ni < 2; ni++) {
                accX[mi][ni] = __builtin_amdgcn_mfma_f32_16x16x32_f16(a1, b1f[ni], accX[mi][ni], 0, 0, 0);
                accY[mi][ni] = __builtin_amdgcn_mfma_f32_16x16x32_f16(a2, b2f[ni], accY[mi][ni], 0, 0, 0);
            }
        }
        __syncthreads();
    }
#pragma unroll
    for (int mi = 0; mi < 4; mi++)
#pragma unroll
        for (int ni = 0; ni < 2; ni++) {
            int row0 = mb + wr * 64 + mi * 16 + quad * 4;
            int col = nb + wc * 32 + ni * 16 + r;
#pragma unroll
            for (int rr = 0; rr < 4; rr++) {
                float val = fmaxf(accY[mi][ni][rr], 0.f) * fmaxf(accX[mi][ni][rr], 0.f);
                C[(long long)(row0 + rr) * MHk + col] = (half_t)val;
            }
        }
}

// ---------------------------------------------------------------------------
// Update: upd += y @ enc_h, 128x128, split-K atomics.
// A=y16 [BT][M] (lda=MHk); B=eT head window [D][8192] (ldb=BTk).
// z = K-chunk of 512 (4 over M=2048).
__global__ __launch_bounds__(256) void gemm128u(
    const half_t* __restrict__ A, const half_t* __restrict__ B,
    float* __restrict__ upd) {
    __shared__ __align__(16) half_t As[128 * 32];
    __shared__ __align__(16) half_t Bs[128 * 32];
    const int tid = threadIdx.x;
    const int lane = tid & 63, wv = tid >> 6;
    const int wr = wv >> 1, wc = wv & 1;
    const int quad = lane >> 4, r = lane & 15;
    const int mb = blockIdx.y * 128, nb = blockIdx.x * 128;
    const int kbeg = blockIdx.z * 512;

    f32x4 acc[4][4] = {};
    const int srow = tid >> 2, skq = (tid & 3) * 8;
    const int wbase = (tid & 192) * 8;
    for (int k0 = kbeg; k0 < kbeg + 512; k0 += 32) {
#pragma unroll
        for (int rnd = 0; rnd < 2; rnd++) {
            int row = rnd * 64 + srow;
            glds16(A + (long long)(mb + row) * MHk + k0 + skq, As + rnd * 2048 + wbase);
            glds16(B + (long long)(nb + row) * BTk + k0 + skq, Bs + rnd * 2048 + wbase);
        }
        __syncthreads();
        half8 bfr[4];
#pragma unroll
        for (int ni = 0; ni < 4; ni++)
            bfr[ni] = *(const half8*)&Bs[(wc * 64 + ni * 16 + r) * 32 + quad * 8];
#pragma unroll
        for (int mi = 0; mi < 4; mi++) {
            half8 afr = *(const half8*)&As[(wr * 64 + mi * 16 + r) * 32 + quad * 8];
#pragma unroll
            for (int ni = 0; ni < 4; ni++)
                acc[mi][ni] = __builtin_amdgcn_mfma_f32_16x16x32_f16(afr, bfr[ni], acc[mi][ni], 0, 0, 0);
        }
        __syncthreads();
    }
#pragma unroll
    for (int mi = 0; mi < 4; mi++)
#pragma unroll
        for (int ni = 0; ni < 4; ni++) {
            int row0 = mb + wr * 64 + mi * 16 + quad * 4;
            int col = nb + wc * 64 + ni * 16 + r;
#pragma unroll
            for (int rr = 0; rr < 4; rr++)
                atomicAdd(&upd[(long long)(row0 + rr) * Dk + col], acc[mi][ni][rr]);
        }
}

// ---------------------------------------------------------------------------
// Plain fp16 64x64 async GEMM, fp32 store — readout. A [M][K], B [N][K].
__global__ __launch_bounds__(256) void gemm64h(
    const half_t* __restrict__ A, int lda,
    const half_t* __restrict__ B, int ldb,
    float* __restrict__ C, int ldc, int K) {
    __shared__ __align__(16) half_t As[64 * 32];
    __shared__ __align__(16) half_t Bs[64 * 32];
    const int tid = threadIdx.x;
    const int lane = tid & 63, wv = tid >> 6;
    const int wr = wv >> 1, wc = wv & 1;
    const int quad = lane >> 4, r = lane & 15;
    const int mb = blockIdx.y * 64, nb = blockIdx.x * 64;

    f32x4 acc[2][2] = {};
    const int srow = tid >> 2, skq = (tid & 3) * 8;
    const int wbase = (tid & 192) * 8;
    for (int k0 = 0; k0 < K; k0 += 32) {
        glds16(A + (long long)(mb + srow) * lda + k0 + skq, As + wbase);
        glds16(B + (long long)(nb + srow) * ldb + k0 + skq, Bs + wbase);
        __syncthreads();
        half8 b0 = *(const half8*)&Bs[(wc * 32 +  0 + r) * 32 + quad * 8];
        half8 b1 = *(const half8*)&Bs[(wc * 32 + 16 + r) * 32 + quad * 8];
#pragma unroll
        for (int mi = 0; mi < 2; mi++) {
            half8 afr = *(const half8*)&As[(wr * 32 + mi * 16 + r) * 32 + quad * 8];
            acc[mi][0] = __builtin_amdgcn_mfma_f32_16x16x32_f16(afr, b0, acc[mi][0], 0, 0, 0);
            acc[mi][1] = __builtin_amdgcn_mfma_f32_16x16x32_f16(afr, b1, acc[mi][1], 0, 0, 0);
        }
        __syncthreads();
    }
#pragma unroll
    for (int mi = 0; mi < 2; mi++)
#pragma unroll
        for (int ni = 0; ni < 2; ni++) {
            int row0 = mb + wr * 32 + mi * 16 + quad * 4;
            int col = nb + wc * 32 + ni * 16 + r;
#pragma unroll
            for (int rr = 0; rr < 4; rr++)
                C[(long long)(row0 + rr) * ldc + col] = acc[mi][ni][rr];
        }
}

// ---------------------------------------------------------------------------
extern "C" void kernel_launch(void* const* d_in, const int* in_sizes, int n_in,
                              void* d_out, int out_size, void* d_ws, size_t ws_size,
                              hipStream_t stream) {
    (void)in_sizes; (void)n_in; (void)out_size; (void)ws_size;
    const int* idx = (const int*)d_in[0];
    float* out = (float*)d_out;

    char* ws = (char*)d_ws;
    float*  v32  = (float*) (ws);                   //  8 MiB [8192][256]
    half_t* vf   = (half_t*)(ws + ( 8ll << 20));    //  4
    half_t* qf   = (half_t*)(ws + (12ll << 20));    //  4
    half_t* vT   = (half_t*)(ws + (16ll << 20));    //  4 [256][8192]
    float*  a32  = (float*) (ws + (20ll << 20));    //  8 (alias upd: phase-disjoint)
    float*  upd  = a32;
    half_t* lnf  = (half_t*)(ws + (28ll << 20));    //  4
    half_t* E    = (half_t*)(ws + (32ll << 20));    // 32 [4][2048][2048] f16
    half_t* y16  = (half_t*)(ws + (64ll << 20));    // 32 [8192][2048] f16
    half_t* dxT  = (half_t*)(ws + (96ll << 20));    //  4 [H][M][D]
    half_t* dyT  = (half_t*)(ws + (100ll << 20));   //  4
    half_t* eT   = (half_t*)(ws + (104ll << 20));   //  4 [256][8192]
    half_t* roT  = (half_t*)(ws + (108ll << 20));   //  128 KiB [256][256]
    int*    flag = (int*)   (ws + (108ll << 20) + (256ll << 10));
    // total ~108.3 MiB (proven footprint)

    sniff_kernel<<<1, 256, 0, stream>>>((const unsigned short*)d_in[1], flag);
    tr_cvt16_kernel<<<dim3(MHk / 32, Dk / 32, 4), 256, 0, stream>>>(
        d_in[3], flag, dxT, Dk, MHk, (long long)Dk * MHk, (long long)Dk * MHk);
    tr_cvt16_kernel<<<dim3(MHk / 32, Dk / 32, 4), 256, 0, stream>>>(
        d_in[4], flag, dyT, Dk, MHk, (long long)Dk * MHk, (long long)Dk * MHk);
    tr_cvt16_kernel<<<dim3(Dk / 32, BTk / 32, 1), 256, 0, stream>>>(
        d_in[2], flag, eT, BTk, Dk, 0, 0);
    tr_cvt16_kernel<<<dim3(Dk / 32, Dk / 32, 1), 256, 0, stream>>>(
        d_in[5], flag, roT, Dk, Dk, 0, 0);

    embed_ln_kernel<<<BTk, 256, 0, stream>>>(idx, d_in[1], flag, v32, vf);

    for (int l = 0; l < LAYERS; l++) {
        rope_kernel<<<BTk, 128, 0, stream>>>(v32, qf);
        trv_kernel<<<dim3(Dk / 32, BTk / 32), 256, 0, stream>>>(v32, vT);
        // E[b] = tril(Qr Qr^T), fp16, all 4 batches
        gemm128e<<<dim3(Tk / 128, Tk / 128, 4), 256, 0, stream>>>(qf, E);
        // a32 = E @ v via 128-tile split-K atomics (pre-zeroed)
        hipMemsetAsync(a32, 0, BTD * sizeof(float), stream);
        gemm128a<<<dim3(Dk / 128, Tk / 128, 16), 256, 0, stream>>>(E, vT, a32);
        ln_rows_kernel<<<BTk, 256, 0, stream>>>(a32, lnf);
        // decoder: per head, fused dual GEMM then 128-tile split-K update
        hipMemsetAsync(upd, 0, BTD * sizeof(float), stream);
        for (int h = 0; h < 4; h++) {
            const long long wofs = (long long)h * MHk * Dk;
            dual_gemm<<<dim3(MHk / 128, BTk / 128), 512, 0, stream>>>(
                vf, lnf, dxT + wofs, dyT + wofs, y16);
            gemm128u<<<dim3(Dk / 128, BTk / 128, 4), 256, 0, stream>>>(
                y16, eT + (long long)h * MHk, upd);
        }
        add_ln_kernel<<<BTk, 256, 0, stream>>>(upd, v32, vf);
    }
    // logits = vf @ roT^T -> fp32 out
    gemm64h<<<dim3(Dk / 64, BTk / 64), 256, 0, stream>>>(
        vf, Dk, roT, Dk, out, Dk, Dk);
}

// Round 9
// 1467.798 us; speedup vs baseline: 6.5776x; 1.5181x over previous
//
#include <hip/hip_runtime.h>
#include <hip/hip_bf16.h>

typedef __hip_bfloat16 bf16;
typedef _Float16 half_t;
typedef __attribute__((ext_vector_type(8))) _Float16 half8;
typedef __attribute__((ext_vector_type(4))) float f32x4;

#define LN_EPS 1e-5f

static constexpr int Dk     = 256;   // model dim
static constexpr int Tk     = 2048;  // seq len
static constexpr int BTk    = 8192;  // B*T
static constexpr int MHk    = 2048;  // N/H
static constexpr int Nk     = 8192;  // hidden
static constexpr int LAYERS = 6;
static constexpr long long TD  = (long long)Tk * Dk;    // 524288
static constexpr long long BTD = (long long)BTk * Dk;   // 2097152
static constexpr long long TT  = (long long)Tk * Tk;    // 4194304

// ---------------------------------------------------------------------------
__device__ __forceinline__ float wave_reduce(float v) {
#pragma unroll
    for (int o = 32; o > 0; o >>= 1) v += __shfl_down(v, o);
    return v;
}

__device__ __forceinline__ float block_sum_256(float x, float* sbuf) {
    float s = wave_reduce(x);
    int lane = threadIdx.x & 63, wv = threadIdx.x >> 6;
    if (lane == 0) sbuf[wv] = s;
    __syncthreads();
    float r = sbuf[0] + sbuf[1] + sbuf[2] + sbuf[3];
    __syncthreads();
    return r;
}

// async global->LDS, 16B/lane; LDS base wave-uniform, HW appends lane*16.
__device__ __forceinline__ void glds16(const void* g, void* lds) {
    __builtin_amdgcn_global_load_lds(
        (const __attribute__((address_space(1))) void*)g,
        (__attribute__((address_space(3))) void*)lds, 16, 0, 0);
}

// ---------------------------------------------------------------------------
// input dtype sniffer (insurance; inputs confirmed fp32)
__global__ __launch_bounds__(256) void sniff_kernel(const unsigned short* __restrict__ w,
                                                    int* __restrict__ flag) {
    __shared__ float sbuf[4];
    int tid = threadIdx.x;
    float cnt = 0.f;
    for (int i = tid; i < 1024; i += 256) {
        int e = (w[i] >> 7) & 0xFF;
        if (e >= 128) cnt += 1.f;
    }
    float tot = block_sum_256(cnt, sbuf);
    if (tid == 0) *flag = (tot > 32.f) ? 1 : 0;
}

// transpose + fp16 convert: src [R][C] (per z) -> dst [C][R] fp16
__global__ __launch_bounds__(256) void tr_cvt16_kernel(const void* __restrict__ src,
                                                       const int* __restrict__ flag,
                                                       half_t* __restrict__ dst,
                                                       int R, int C,
                                                       long long sz, long long dz) {
    __shared__ float t[32][33];
    bool f32 = (*flag != 0);
    int ct = blockIdx.x * 32, rt = blockIdx.y * 32;
    long long so = (long long)blockIdx.z * sz, dofs = (long long)blockIdx.z * dz;
    int tx = threadIdx.x & 31, ty = threadIdx.x >> 5;
#pragma unroll
    for (int i = 0; i < 4; i++) {
        long long idx = so + (long long)(rt + ty + i * 8) * C + ct + tx;
        t[ty + i * 8][tx] = f32 ? ((const float*)src)[idx] : (float)((const bf16*)src)[idx];
    }
    __syncthreads();
#pragma unroll
    for (int i = 0; i < 4; i++) {
        long long odx = dofs + (long long)(ct + ty + i * 8) * R + rt + tx;
        dst[odx] = (half_t)t[tx][ty + i * 8];
    }
}

// v32 [BT][D] fp32 -> vT [D][BT] fp16
__global__ __launch_bounds__(256) void trv_kernel(const float* __restrict__ src,
                                                  half_t* __restrict__ dst) {
    __shared__ float t[32][33];
    int ct = blockIdx.x * 32, rt = blockIdx.y * 32;
    int tx = threadIdx.x & 31, ty = threadIdx.x >> 5;
#pragma unroll
    for (int i = 0; i < 4; i++)
        t[ty + i * 8][tx] = src[(long long)(rt + ty + i * 8) * Dk + ct + tx];
    __syncthreads();
#pragma unroll
    for (int i = 0; i < 4; i++)
        dst[(long long)(ct + ty + i * 8) * BTk + rt + tx] = (half_t)t[tx][ty + i * 8];
}

// ---------------------------------------------------------------------------
// v = layernorm(wte[idx]) -> v32 fp32, vf fp16
__global__ __launch_bounds__(256) void embed_ln_kernel(const int* __restrict__ idx,
                                                       const void* __restrict__ wte,
                                                       const int* __restrict__ flag,
                                                       float* __restrict__ v,
                                                       half_t* __restrict__ vf) {
    __shared__ float sbuf[4];
    int bt = blockIdx.x, tid = threadIdx.x;
    int id = idx[bt];
    bool f32 = (*flag != 0);
    float x = f32 ? ((const float*)wte)[id * Dk + tid]
                  : (float)((const bf16*)wte)[id * Dk + tid];
    float mu = block_sum_256(x, sbuf) * (1.f / 256.f);
    float d = x - mu;
    float var = block_sum_256(d * d, sbuf) * (1.f / 256.f);
    float r = d * rsqrtf(var + LN_EPS);
    v[bt * Dk + tid] = r;
    vf[bt * Dk + tid] = (half_t)r;
}

// lnf = fp16(layernorm(sum of alive a-partials)).
// Row t (in batch): alive chunks c with c*512 <= (t & ~127).
__global__ __launch_bounds__(256) void ln_rows_kernel(const float* __restrict__ Pa,
                                                      half_t* __restrict__ of) {
    __shared__ float sbuf[4];
    int bt = blockIdx.x, tid = threadIdx.x;
    int b = bt >> 11, t = bt & (Tk - 1);
    int ncnt = ((t & ~127) >> 9) + 1;
    const float* p = Pa + ((long long)(b << 2)) * TD + (long long)t * Dk + tid;
    float x = 0.f;
    for (int c = 0; c < ncnt; c++) x += p[(long long)c * TD];
    float mu = block_sum_256(x, sbuf) * (1.f / 256.f);
    float d = x - mu;
    float var = block_sum_256(d * d, sbuf) * (1.f / 256.f);
    float r = d * rsqrtf(var + LN_EPS);
    of[bt * Dk + tid] = (half_t)r;
}

// v += layernorm(sum of 4 update-partials) -> refresh v32, vf
__global__ __launch_bounds__(256) void add_ln_kernel(const float* __restrict__ Pu,
                                                     float* __restrict__ v,
                                                     half_t* __restrict__ vf) {
    __shared__ float sbuf[4];
    int bt = blockIdx.x, tid = threadIdx.x;
    long long e = (long long)bt * Dk + tid;
    float x = Pu[e] + Pu[e + BTD] + Pu[e + 2 * BTD] + Pu[e + 3 * BTD];
    float mu = block_sum_256(x, sbuf) * (1.f / 256.f);
    float d = x - mu;
    float var = block_sum_256(d * d, sbuf) * (1.f / 256.f);
    float r = d * rsqrtf(var + LN_EPS);
    float nv = v[e] + r;
    v[e] = nv;
    vf[e] = (half_t)nv;
}

// RoPE from fp32 v -> qf fp16 (Q == K)
__global__ __launch_bounds__(128) void rope_kernel(const float* __restrict__ v,
                                                   half_t* __restrict__ qf) {
    int bt = blockIdx.x, i = threadIdx.x;
    int t = bt & (Tk - 1);
    float invf = powf(10000.f, -(float)i / 128.f);
    float ang = (float)t * invf;
    float s, c;
    sincosf(ang, &s, &c);
    float q1 = v[bt * Dk + i];
    float q2 = v[bt * Dk + 128 + i];
    qf[bt * Dk + i]       = (half_t)(q1 * c - q2 * s);
    qf[bt * Dk + 128 + i] = (half_t)(q2 * c + q1 * s);
}

// ---------------------------------------------------------------------------
// Energy: E[b] = tril(Qr Qr^T), fp16, 128x128 async GEMM, z = batch.
__global__ __launch_bounds__(256) void gemm128e(
    const half_t* __restrict__ Q, half_t* __restrict__ E) {
    __shared__ __align__(16) half_t As[128 * 32];
    __shared__ __align__(16) half_t Bs[128 * 32];
    const int tid = threadIdx.x;
    const int lane = tid & 63, wv = tid >> 6;
    const int wr = wv >> 1, wc = wv & 1;
    const int quad = lane >> 4, r = lane & 15;
    const int mb = blockIdx.y * 128, nb = blockIdx.x * 128;
    const half_t* Qb = Q + (long long)blockIdx.z * TD;
    half_t* Eb = E + (long long)blockIdx.z * TT;

    if ((int)blockIdx.x > (int)blockIdx.y) {
#pragma unroll
        for (int e = 0; e < 64; e++) {
            int ii = e * 256 + tid;
            Eb[(long long)(mb + (ii >> 7)) * Tk + nb + (ii & 127)] = (half_t)0.f;
        }
        return;
    }

    f32x4 acc[4][4] = {};
    const int srow = tid >> 2, skq = (tid & 3) * 8;
    const int wbase = (tid & 192) * 8;
    for (int k0 = 0; k0 < Dk; k0 += 32) {
#pragma unroll
        for (int rnd = 0; rnd < 2; rnd++) {
            int row = rnd * 64 + srow;
            glds16(Qb + (long long)(mb + row) * Dk + k0 + skq, As + rnd * 2048 + wbase);
            glds16(Qb + (long long)(nb + row) * Dk + k0 + skq, Bs + rnd * 2048 + wbase);
        }
        __syncthreads();
        half8 bfr[4];
#pragma unroll
        for (int ni = 0; ni < 4; ni++)
            bfr[ni] = *(const half8*)&Bs[(wc * 64 + ni * 16 + r) * 32 + quad * 8];
#pragma unroll
        for (int mi = 0; mi < 4; mi++) {
            half8 afr = *(const half8*)&As[(wr * 64 + mi * 16 + r) * 32 + quad * 8];
#pragma unroll
            for (int ni = 0; ni < 4; ni++)
                acc[mi][ni] = __builtin_amdgcn_mfma_f32_16x16x32_f16(afr, bfr[ni], acc[mi][ni], 0, 0, 0);
        }
        __syncthreads();
    }
#pragma unroll
    for (int mi = 0; mi < 4; mi++)
#pragma unroll
        for (int ni = 0; ni < 4; ni++) {
            int row0 = mb + wr * 64 + mi * 16 + quad * 4;
            int col = nb + wc * 64 + ni * 16 + r;
#pragma unroll
            for (int rr = 0; rr < 4; rr++) {
                int row = row0 + rr;
                float val = (row < col) ? 0.f : acc[mi][ni][rr];
                Eb[(long long)row * Tk + col] = (half_t)val;
            }
        }
}

// ---------------------------------------------------------------------------
// a-GEMM: Pa[z] = E_chunk @ V, 128x128, split-K partial stores (no atomics).
// z = b*4 + c (batch, K-chunk of 512). Causal: dead chunks skipped (ln_rows
// only reads alive chunks).
__global__ __launch_bounds__(256) void gemm128a(
    const half_t* __restrict__ E, const half_t* __restrict__ vT,
    float* __restrict__ Pa) {
    __shared__ __align__(16) half_t As[128 * 32];
    __shared__ __align__(16) half_t Bs[128 * 32];
    const int tid = threadIdx.x;
    const int lane = tid & 63, wv = tid >> 6;
    const int wr = wv >> 1, wc = wv & 1;
    const int quad = lane >> 4, r = lane & 15;
    const int mb = blockIdx.y * 128, nb = blockIdx.x * 128;
    const int b = blockIdx.z >> 2, c = blockIdx.z & 3;
    const int kbeg = c * 512;
    const int kend = min(mb + 128, kbeg + 512);
    if (kend <= kbeg) return;

    const half_t* Ab = E + (long long)b * TT;
    const half_t* Bb = vT + (long long)b * Tk;
    float* Pc = Pa + (long long)blockIdx.z * TD;
    f32x4 acc[4][4] = {};
    const int srow = tid >> 2, skq = (tid & 3) * 8;
    const int wbase = (tid & 192) * 8;
    for (int k0 = kbeg; k0 < kend; k0 += 32) {
#pragma unroll
        for (int rnd = 0; rnd < 2; rnd++) {
            int row = rnd * 64 + srow;
            glds16(Ab + (long long)(mb + row) * Tk + k0 + skq, As + rnd * 2048 + wbase);
            glds16(Bb + (long long)(nb + row) * BTk + k0 + skq, Bs + rnd * 2048 + wbase);
        }
        __syncthreads();
        half8 bfr[4];
#pragma unroll
        for (int ni = 0; ni < 4; ni++)
            bfr[ni] = *(const half8*)&Bs[(wc * 64 + ni * 16 + r) * 32 + quad * 8];
#pragma unroll
        for (int mi = 0; mi < 4; mi++) {
            half8 afr = *(const half8*)&As[(wr * 64 + mi * 16 + r) * 32 + quad * 8];
#pragma unroll
            for (int ni = 0; ni < 4; ni++)
                acc[mi][ni] = __builtin_amdgcn_mfma_f32_16x16x32_f16(afr, bfr[ni], acc[mi][ni], 0, 0, 0);
        }
        __syncthreads();
    }
#pragma unroll
    for (int mi = 0; mi < 4; mi++)
#pragma unroll
        for (int ni = 0; ni < 4; ni++) {
            int row0 = mb + wr * 64 + mi * 16 + quad * 4;
            int col = nb + wc * 64 + ni * 16 + r;
#pragma unroll
            for (int rr = 0; rr < 4; rr++)
                Pc[(long long)(row0 + rr) * Dk + col] = acc[mi][ni][rr];
        }
}

// ---------------------------------------------------------------------------
// Fused dual fp16 GEMM, 512 threads (8 waves, 2x4), 128x128 tile, z = head:
//   y[:, h*M + n] = relu(lnf @ dyT_h) * relu(vf @ dxT_h), fp16 out [BT][Nk].
__global__ __launch_bounds__(512) void dual_gemm(
    const half_t* __restrict__ A1,   // vf  [BT][D]
    const half_t* __restrict__ A2,   // lnf [BT][D]
    const half_t* __restrict__ dxT,  // [H][M][D]
    const half_t* __restrict__ dyT,  // [H][M][D]
    half_t* __restrict__ C) {        // y16 [BT][Nk]
    __shared__ __align__(16) half_t As1[128 * 32];
    __shared__ __align__(16) half_t As2[128 * 32];
    __shared__ __align__(16) half_t Bs1[128 * 32];
    __shared__ __align__(16) half_t Bs2[128 * 32];
    const int tid = threadIdx.x;
    const int lane = tid & 63, wv = tid >> 6;     // 8 waves
    const int wr = wv >> 2, wc = wv & 3;          // 2 x 4 wave grid
    const int quad = lane >> 4, r = lane & 15;
    const int mb = blockIdx.y * 128, nb = blockIdx.x * 128;
    const int h = blockIdx.z;
    const half_t* B1 = dxT + (long long)h * MHk * Dk;
    const half_t* B2 = dyT + (long long)h * MHk * Dk;

    f32x4 accX[4][2] = {};
    f32x4 accY[4][2] = {};
    const int srow = tid >> 2, skq = (tid & 3) * 8;   // 512 thr: whole 128x32 tile per glds
    const int wbase = (tid & 448) * 8;                // wv * 512 elems
    for (int k0 = 0; k0 < Dk; k0 += 32) {
        glds16(A1 + (long long)(mb + srow) * Dk + k0 + skq, As1 + wbase);
        glds16(A2 + (long long)(mb + srow) * Dk + k0 + skq, As2 + wbase);
        glds16(B1 + (long long)(nb + srow) * Dk + k0 + skq, Bs1 + wbase);
        glds16(B2 + (long long)(nb + srow) * Dk + k0 + skq, Bs2 + wbase);
        __syncthreads();
        half8 b1f[2], b2f[2];
#pragma unroll
        for (int ni = 0; ni < 2; ni++) {
            b1f[ni] = *(const half8*)&Bs1[(wc * 32 + ni * 16 + r) * 32 + quad * 8];
            b2f[ni] = *(const half8*)&Bs2[(wc * 32 + ni * 16 + r) * 32 + quad * 8];
        }
#pragma unroll
        for (int mi = 0; mi < 4; mi++) {
            half8 a1 = *(const half8*)&As1[(wr * 64 + mi * 16 + r) * 32 + quad * 8];
            half8 a2 = *(const half8*)&As2[(wr * 64 + mi * 16 + r) * 32 + quad * 8];
#pragma unroll
            for (int ni = 0; ni < 2; ni++) {
                accX[mi][ni] = __builtin_amdgcn_mfma_f32_16x16x32_f16(a1, b1f[ni], accX[mi][ni], 0, 0, 0);
                accY[mi][ni] = __builtin_amdgcn_mfma_f32_16x16x32_f16(a2, b2f[ni], accY[mi][ni], 0, 0, 0);
            }
        }
        __syncthreads();
    }
#pragma unroll
    for (int mi = 0; mi < 4; mi++)
#pragma unroll
        for (int ni = 0; ni < 2; ni++) {
            int row0 = mb + wr * 64 + mi * 16 + quad * 4;
            int col = h * MHk + nb + wc * 32 + ni * 16 + r;
#pragma unroll
            for (int rr = 0; rr < 4; rr++) {
                float val = fmaxf(accY[mi][ni][rr], 0.f) * fmaxf(accX[mi][ni][rr], 0.f);
                C[(long long)(row0 + rr) * Nk + col] = (half_t)val;
            }
        }
}

// ---------------------------------------------------------------------------
// Update: Pu[z] = y @ enc over K-chunk z*2048, 128x128, partial stores.
// A=y16 [BT][Nk]; B=eT [D][Nk]. add_ln sums the 4 partials.
__global__ __launch_bounds__(256) void gemm128u(
    const half_t* __restrict__ A, const half_t* __restrict__ B,
    float* __restrict__ Pu) {
    __shared__ __align__(16) half_t As[128 * 32];
    __shared__ __align__(16) half_t Bs[128 * 32];
    const int tid = threadIdx.x;
    const int lane = tid & 63, wv = tid >> 6;
    const int wr = wv >> 1, wc = wv & 1;
    const int quad = lane >> 4, r = lane & 15;
    const int mb = blockIdx.y * 128, nb = blockIdx.x * 128;
    const int kbeg = blockIdx.z * 2048;
    float* Pc = Pu + (long long)blockIdx.z * BTD;

    f32x4 acc[4][4] = {};
    const int srow = tid >> 2, skq = (tid & 3) * 8;
    const int wbase = (tid & 192) * 8;
    for (int k0 = kbeg; k0 < kbeg + 2048; k0 += 32) {
#pragma unroll
        for (int rnd = 0; rnd < 2; rnd++) {
            int row = rnd * 64 + srow;
            glds16(A + (long long)(mb + row) * Nk + k0 + skq, As + rnd * 2048 + wbase);
            glds16(B + (long long)(nb + row) * Nk + k0 + skq, Bs + rnd * 2048 + wbase);
        }
        __syncthreads();
        half8 bfr[4];
#pragma unroll
        for (int ni = 0; ni < 4; ni++)
            bfr[ni] = *(const half8*)&Bs[(wc * 64 + ni * 16 + r) * 32 + quad * 8];
#pragma unroll
        for (int mi = 0; mi < 4; mi++) {
            half8 afr = *(const half8*)&As[(wr * 64 + mi * 16 + r) * 32 + quad * 8];
#pragma unroll
            for (int ni = 0; ni < 4; ni++)
                acc[mi][ni] = __builtin_amdgcn_mfma_f32_16x16x32_f16(afr, bfr[ni], acc[mi][ni], 0, 0, 0);
        }
        __syncthreads();
    }
#pragma unroll
    for (int mi = 0; mi < 4; mi++)
#pragma unroll
        for (int ni = 0; ni < 4; ni++) {
            int row0 = mb + wr * 64 + mi * 16 + quad * 4;
            int col = nb + wc * 64 + ni * 16 + r;
#pragma unroll
            for (int rr = 0; rr < 4; rr++)
                Pc[(long long)(row0 + rr) * Dk + col] = acc[mi][ni][rr];
        }
}

// ---------------------------------------------------------------------------
// Plain fp16 64x64 async GEMM, fp32 store — readout. A [M][K], B [N][K].
__global__ __launch_bounds__(256) void gemm64h(
    const half_t* __restrict__ A, int lda,
    const half_t* __restrict__ B, int ldb,
    float* __restrict__ C, int ldc, int K) {
    __shared__ __align__(16) half_t As[64 * 32];
    __shared__ __align__(16) half_t Bs[64 * 32];
    const int tid = threadIdx.x;
    const int lane = tid & 63, wv = tid >> 6;
    const int wr = wv >> 1, wc = wv & 1;
    const int quad = lane >> 4, r = lane & 15;
    const int mb = blockIdx.y * 64, nb = blockIdx.x * 64;

    f32x4 acc[2][2] = {};
    const int srow = tid >> 2, skq = (tid & 3) * 8;
    const int wbase = (tid & 192) * 8;
    for (int k0 = 0; k0 < K; k0 += 32) {
        glds16(A + (long long)(mb + srow) * lda + k0 + skq, As + wbase);
        glds16(B + (long long)(nb + srow) * ldb + k0 + skq, Bs + wbase);
        __syncthreads();
        half8 b0 = *(const half8*)&Bs[(wc * 32 +  0 + r) * 32 + quad * 8];
        half8 b1 = *(const half8*)&Bs[(wc * 32 + 16 + r) * 32 + quad * 8];
#pragma unroll
        for (int mi = 0; mi < 2; mi++) {
            half8 afr = *(const half8*)&As[(wr * 32 + mi * 16 + r) * 32 + quad * 8];
            acc[mi][0] = __builtin_amdgcn_mfma_f32_16x16x32_f16(afr, b0, acc[mi][0], 0, 0, 0);
            acc[mi][1] = __builtin_amdgcn_mfma_f32_16x16x32_f16(afr, b1, acc[mi][1], 0, 0, 0);
        }
        __syncthreads();
    }
#pragma unroll
    for (int mi = 0; mi < 2; mi++)
#pragma unroll
        for (int ni = 0; ni < 2; ni++) {
            int row0 = mb + wr * 32 + mi * 16 + quad * 4;
            int col = nb + wc * 32 + ni * 16 + r;
#pragma unroll
            for (int rr = 0; rr < 4; rr++)
                C[(long long)(row0 + rr) * ldc + col] = acc[mi][ni][rr];
        }
}

// ---------------------------------------------------------------------------
extern "C" void kernel_launch(void* const* d_in, const int* in_sizes, int n_in,
                              void* d_out, int out_size, void* d_ws, size_t ws_size,
                              hipStream_t stream) {
    (void)in_sizes; (void)n_in; (void)out_size; (void)ws_size;
    const int* idx = (const int*)d_in[0];
    float* out = (float*)d_out;

    char* ws = (char*)d_ws;
    float*  v32  = (float*) (ws);                   //   8 MiB [8192][256]
    half_t* vf   = (half_t*)(ws + (  8ll << 20));   //   4
    half_t* qf   = (half_t*)(ws + ( 12ll << 20));   //   4
    half_t* vT   = (half_t*)(ws + ( 16ll << 20));   //   4 [256][8192]
    half_t* lnf  = (half_t*)(ws + ( 20ll << 20));   //   4
    half_t* E    = (half_t*)(ws + ( 24ll << 20));   //  32 [4][2048][2048] f16
    float*  Pa   = (float*) (ws + ( 56ll << 20));   //  32 [16][2048][256] f32
    float*  Pu   = (float*) (ws + ( 24ll << 20));   //  64 [4][8192][256] f32 (aliases E+Pa, phase-disjoint)
    half_t* y16  = (half_t*)(ws + ( 88ll << 20));   // 128 [8192][8192] f16
    half_t* dxT  = (half_t*)(ws + (216ll << 20));   //   4 [H][M][D]
    half_t* dyT  = (half_t*)(ws + (220ll << 20));   //   4
    half_t* eT   = (half_t*)(ws + (224ll << 20));   //   4 [256][8192]
    half_t* roT  = (half_t*)(ws + (228ll << 20));   // 128 KiB [256][256]
    int*    flag = (int*)   (ws + (228ll << 20) + (256ll << 10));
    // total ~229 MiB (ws_size = 256 MiB per harness poison-fill size)

    sniff_kernel<<<1, 256, 0, stream>>>((const unsigned short*)d_in[1], flag);
    tr_cvt16_kernel<<<dim3(MHk / 32, Dk / 32, 4), 256, 0, stream>>>(
        d_in[3], flag, dxT, Dk, MHk, (long long)Dk * MHk, (long long)Dk * MHk);
    tr_cvt16_kernel<<<dim3(MHk / 32, Dk / 32, 4), 256, 0, stream>>>(
        d_in[4], flag, dyT, Dk, MHk, (long long)Dk * MHk, (long long)Dk * MHk);
    tr_cvt16_kernel<<<dim3(Dk / 32, Nk / 32, 1), 256, 0, stream>>>(
        d_in[2], flag, eT, Nk, Dk, 0, 0);
    tr_cvt16_kernel<<<dim3(Dk / 32, Dk / 32, 1), 256, 0, stream>>>(
        d_in[5], flag, roT, Dk, Dk, 0, 0);

    embed_ln_kernel<<<BTk, 256, 0, stream>>>(idx, d_in[1], flag, v32, vf);

    for (int l = 0; l < LAYERS; l++) {
        rope_kernel<<<BTk, 128, 0, stream>>>(v32, qf);
        trv_kernel<<<dim3(Dk / 32, BTk / 32), 256, 0, stream>>>(v32, vT);
        // E[b] = tril(Qr Qr^T), fp16, all 4 batches
        gemm128e<<<dim3(Tk / 128, Tk / 128, 4), 256, 0, stream>>>(qf, E);
        // Pa[b*4+c] = E_chunk @ v (partials; dead causal chunks skipped)
        gemm128a<<<dim3(Dk / 128, Tk / 128, 16), 256, 0, stream>>>(E, vT, Pa);
        // lnf = LN(sum of alive partials)
        ln_rows_kernel<<<BTk, 256, 0, stream>>>(Pa, lnf);
        // y (all 4 heads, one dispatch)
        dual_gemm<<<dim3(MHk / 128, BTk / 128, 4), 512, 0, stream>>>(
            vf, lnf, dxT, dyT, y16);
        // Pu[z] = y @ enc, K-chunk 2048 (partials)
        gemm128u<<<dim3(Dk / 128, BTk / 128, 4), 256, 0, stream>>>(y16, eT, Pu);
        // v += LN(sum of partials)
        add_ln_kernel<<<BTk, 256, 0, stream>>>(Pu, v32, vf);
    }
    // logits = vf @ roT^T -> fp32 out
    gemm64h<<<dim3(Dk / 64, BTk / 64), 256, 0, stream>>>(
        vf, Dk, roT, Dk, out, Dk, Dk);
}